// Round 11
// baseline (489.570 us; speedup 1.0000x reference)
//
#include <hip/hip_runtime.h>
#include <hip/hip_bf16.h>
#include <math.h>

#define NJ 30000
#define NS 12000
#define E_JS 300000
#define E_SJ 300000
#define E_SS 150000
#define ETOT (E_JS + E_SJ + E_SS + NS)   // 762000 incl. ss self loops
#define NBINS (NS + NJ + NS)             // 54000 combined dst bins
#define SBERT 384
#define HIST_NB 512
#define SCAT_NB 480
#define CAST_MATS 14
#define CAST_BPM 48
#define PREP_CAST (CAST_MATS * CAST_BPM)          // 672
#define PREP_WA   (PREP_CAST + 192)               // 864 (quarter-wave per output)
#define PREP_QV   PREP_WA                         // 864
#define PREP_GB   (PREP_QV + 1)                   // 865
#define PREP_HIST (PREP_GB + 1)                   // 866

static inline int cdiv(int a, int b) { return (a + b - 1) / b; }

typedef __attribute__((ext_vector_type(8))) short bf8_t;
typedef __attribute__((ext_vector_type(4))) float f4_t;
typedef unsigned short u16;

__device__ inline float bf2f(unsigned short u) {
    union { unsigned int i; float f; } z; z.i = ((unsigned int)u) << 16; return z.f;
}
__device__ inline unsigned short f2bf(float f) {
    unsigned int x = __float_as_uint(f);
    unsigned int r = (x + 0x7fffu + ((x >> 16) & 1u)) >> 16;   // RNE
    return (unsigned short)r;
}

// ---------------------------------------------------------------------------
// edge decode; bin layout: [0,NS) js | [NS,NS+NJ) sj | [NS+NJ,NBINS) ss+loops
// ---------------------------------------------------------------------------
__device__ inline void edge_decode(int e, const int* js_src, const int* js_dst,
                                   const int* sj_src, const int* sj_dst,
                                   const int* ss_src, const int* ss_dst,
                                   int& src, int& bin) {
    if (e < E_JS) { src = js_src[e]; bin = js_dst[e]; }
    else if (e < E_JS + E_SJ) { int i = e - E_JS; src = sj_src[i]; bin = NS + sj_dst[i]; }
    else if (e < E_JS + E_SJ + E_SS) { int i = e - E_JS - E_SJ; src = ss_src[i]; bin = NS + NJ + ss_dst[i]; }
    else { int i = e - E_JS - E_SJ - E_SS; src = i; bin = NS + NJ + i; }
}

// ---------------------------------------------------------------------------
// D1 k_prep: castT [0,672) | wa [672,864) | qvec [864] | gbS [865] | hist...
// bcnt (NBINS ints) / WsS1 / WsJ0 / WsJ1 zeroed by hipMemsetAsync first.
// hist: DIRECT per-bin global atomics (counting-sort CSR; within-bin order
// is arbitrary, same as the old bucket+finalize scheme).
// ---------------------------------------------------------------------------
struct CastT { const float* src; unsigned short* dst; int K; int N; int srcLd; int dstLd; };
struct PrepArgs {
    CastT m[CAST_MATS];
    const float* Ws; const float* as_; const float* Wd; const float* ad_;
    float* wsa; float* wda; int* bcnt;
    const float* query; const float* Wq; const float* bq; float* qv;
    const float* gat_b; float* gbS;
    const int* js_src; const int* js_dst;
    const int* sj_src; const int* sj_dst;
    const int* ss_src; const int* ss_dst;
};

__global__ __launch_bounds__(256) void k_prep(PrepArgs A) {
    __shared__ float ldt[32][33];
    int b = blockIdx.x;
    if (b < PREP_CAST) {
        int mi = b / CAST_BPM, bx = b % CAST_BPM;
        CastT cm = A.m[mi];
        int tilesN = cm.N >> 5;
        int total = (cm.K >> 5) * tilesN;
        if (bx >= total) return;
        int tk = bx / tilesN, tn = bx % tilesN;
        int k0 = tk * 32, n0 = tn * 32;
        int col = threadIdx.x & 31;
        int row0 = threadIdx.x >> 5;
#pragma unroll
        for (int r = 0; r < 4; ++r) {
            int kk = row0 + r * 8;
            ldt[kk][col] = cm.src[(size_t)(k0 + kk) * cm.srcLd + n0 + col];
        }
        __syncthreads();
#pragma unroll
        for (int r = 0; r < 4; ++r) {
            int nn = row0 + r * 8;
            cm.dst[(size_t)(n0 + nn) * cm.dstLd + k0 + col] = f2bf(ldt[col][nn]);
        }
    } else if (b < PREP_WA) {
        int qw = ((b - PREP_CAST) * 256 + threadIdx.x) >> 4;   // quarter-wave id
        int cl = threadIdx.x & 15;
        if (qw < 2 * 1536) {
            int which = qw / 1536;
            int r = qw % 1536;
            int lr = r / 256;
            int kh = r % 256;
            int k = kh / 2, h = kh % 2;
            const float* W = which ? A.Wd : A.Ws;
            const float* a = which ? A.ad_ : A.as_;
            const float* wrow = W + ((size_t)(lr * 128 + k)) * 256 + h * 128 + cl * 8;
            const float* arow = a + (size_t)(lr * 2 + h) * 128 + cl * 8;
            float4 w0 = *(const float4*)wrow, w1 = *(const float4*)(wrow + 4);
            float4 a0 = *(const float4*)arow, a1 = *(const float4*)(arow + 4);
            float acc = w0.x * a0.x + w0.y * a0.y + w0.z * a0.z + w0.w * a0.w
                      + w1.x * a1.x + w1.y * a1.y + w1.z * a1.z + w1.w * a1.w;
            acc += __shfl_xor(acc, 1, 64);
            acc += __shfl_xor(acc, 2, 64);
            acc += __shfl_xor(acc, 4, 64);
            acc += __shfl_xor(acc, 8, 64);
            if (cl == 0) (which ? A.wda : A.wsa)[lr * 256 + k * 2 + h] = acc;
        }
    } else if (b == PREP_QV) {
        int c = threadIdx.x;
        if (c < 128) {
            float acc = A.bq[c];
            for (int k = 0; k < SBERT; ++k) acc += A.query[k] * A.Wq[(size_t)k * 128 + c];
            A.qv[c] = acc;
        }
    } else if (b == PREP_GB) {
        int c = threadIdx.x;
        if (c < 256) A.gbS[c] = A.gat_b[c] + A.gat_b[512 + c];   // gb(0,0)+gb(0,2)
    } else {
        int hb = b - PREP_HIST;
        for (int e = hb * 256 + threadIdx.x; e < ETOT; e += HIST_NB * 256) {
            int src, bin;
            edge_decode(e, A.js_src, A.js_dst, A.sj_src, A.sj_dst, A.ss_src, A.ss_dst, src, bin);
            atomicAdd(&A.bcnt[bin], 1);
        }
    }
}

// ---------------------------------------------------------------------------
// MFMA GEMM body for D2 lin0 (fp32 X, K=384). BM=64, 4 waves x (16m x 128n).
// Round-6 structure (best measured): global_load_lds width-16 into linear LDS,
// XOR-block-swizzled on the GLOBAL source; reads apply the same swizzle.
// ONE barrier per K-step; stage for tile k+1 issued after the barrier.
//   A: fp32 [64][32], 8x16B blocks/row, swz b^=(row&7); bf16-convert at read.
//   B: bf16 [128][32], 4x16B blocks/row, swz b^=((row>>1)&3).
// EPI 3: +bias,LN,relu->bf16, with alpha epilogue (aMode pairs).
// ---------------------------------------------------------------------------
struct GJob {
    const void* X; const unsigned short* Wt;
    const float* bias; const float* gamma; const float* beta;
    void* Y; int M; int K; int N; int ldY; int srcf32;
    const float* qv; float* sc;
    int aMode = 0;
    const float* wav0 = nullptr; const float* wav1 = nullptr;
    const float* wav2 = nullptr; const float* wav3 = nullptr;
    float* aOut = nullptr; int aStride = 0;
};
struct GPair { GJob a; GJob b; int blocksA; };

template <int EPI>
__device__ void mgemm_body(const GPair& P, int bx) {
    int mb = bx;
    GJob g = (mb < P.blocksA) ? P.a : P.b;
    if (mb >= P.blocksA) mb -= P.blocksA;
    const int row0 = mb * 64;

    __shared__ __align__(16) float As[2][64][32];           // 16 KB
    __shared__ __align__(16) unsigned short Bs[2][128][32]; // 16 KB
    const int t = threadIdx.x;
    const int wave = t >> 6, lane = t & 63;
    const int q = lane >> 4, c = lane & 15;
    const int K = g.K;
    const float* Xf = (const float*)g.X;

    f4_t acc[8];
#pragma unroll
    for (int nt = 0; nt < 8; ++nt) acc[nt] = (f4_t){0.f, 0.f, 0.f, 0.f};

    auto STAGE = [&](int cur, int k0) {
#pragma unroll
        for (int i = 0; i < 2; ++i) {
            int bi = i * 256 + t;
            int row = bi >> 3, b = bi & 7;
            int ra = row0 + row; ra = (ra < g.M) ? ra : (g.M - 1);
            const float* gsrc = Xf + (size_t)ra * K + k0 + ((b ^ (row & 7)) << 2);
            __builtin_amdgcn_global_load_lds(
                (__attribute__((address_space(1))) void*)gsrc,
                (__attribute__((address_space(3))) void*)((char*)&As[cur][0][0] + ((i * 4 + wave) << 10)),
                16, 0, 0);
        }
#pragma unroll
        for (int i = 0; i < 2; ++i) {
            int bi = i * 256 + t;
            int row = bi >> 2, b = bi & 3;
            const unsigned short* gsrc = g.Wt + (size_t)row * K + k0 + ((b ^ ((row >> 1) & 3)) << 3);
            __builtin_amdgcn_global_load_lds(
                (__attribute__((address_space(1))) void*)gsrc,
                (__attribute__((address_space(3))) void*)((char*)&Bs[cur][0][0] + ((i * 4 + wave) << 10)),
                16, 0, 0);
        }
    };

    auto MF = [&](int cur) {
        const char* Ab = (const char*)&As[cur][0][0];
        const char* Bb = (const char*)&Bs[cur][0][0];
        int r = wave * 16 + c;
        int sw = r & 7;
        f4_t fa0 = *(const f4_t*)(Ab + r * 128 + (((q * 2) ^ sw) << 4));
        f4_t fa1 = *(const f4_t*)(Ab + r * 128 + (((q * 2 + 1) ^ sw) << 4));
        bf8_t af;
        af[0] = (short)f2bf(fa0[0]); af[1] = (short)f2bf(fa0[1]);
        af[2] = (short)f2bf(fa0[2]); af[3] = (short)f2bf(fa0[3]);
        af[4] = (short)f2bf(fa1[0]); af[5] = (short)f2bf(fa1[1]);
        af[6] = (short)f2bf(fa1[2]); af[7] = (short)f2bf(fa1[3]);
#pragma unroll
        for (int nt = 0; nt < 8; ++nt) {
            int rb = nt * 16 + c;
            bf8_t bfr = *(const bf8_t*)(Bb + rb * 64 + ((q ^ ((rb >> 1) & 3)) << 4));
            acc[nt] = __builtin_amdgcn_mfma_f32_16x16x32_bf16(af, bfr, acc[nt], 0, 0, 0);
        }
    };

    STAGE(0, 0);
    int cur = 0;
    for (int k0 = 0; k0 < K; k0 += 32) {
        asm volatile("s_waitcnt vmcnt(0)" ::: "memory");
        __syncthreads();              // buf[cur] staged by all waves; prior reads done
        if (k0 + 32 < K) STAGE(cur ^ 1, k0 + 32);   // in flight through MF below
        MF(cur);
        cur ^= 1;
    }

    float bcol[8], gcol[8], becol[8];
#pragma unroll
    for (int nt = 0; nt < 8; ++nt) {
        bcol[nt] = g.bias[nt * 16 + c];
        if constexpr (EPI == 3) {
            gcol[nt] = g.gamma[nt * 16 + c];
            becol[nt] = g.beta[nt * 16 + c];
        }
    }

#pragma unroll
    for (int r = 0; r < 4; ++r) {
        int grow = row0 + wave * 16 + q * 4 + r;
        float v[8];
#pragma unroll
        for (int nt = 0; nt < 8; ++nt) v[nt] = acc[nt][r] + bcol[nt];
        if constexpr (EPI == 3) {
            float s = 0.f, ss = 0.f;
#pragma unroll
            for (int nt = 0; nt < 8; ++nt) { s += v[nt]; ss += v[nt] * v[nt]; }
#pragma unroll
            for (int m = 8; m >= 1; m >>= 1) {
                s += __shfl_xor(s, m, 64);
                ss += __shfl_xor(ss, m, 64);
            }
            float mu = s * (1.f / 128.f);
            float var = ss * (1.f / 128.f) - mu * mu;
            float rs = rsqrtf(var + 1e-5f);
#pragma unroll
            for (int nt = 0; nt < 8; ++nt)
                v[nt] = fmaxf((v[nt] - mu) * rs * gcol[nt] + becol[nt], 0.f);
        }
        if (g.aMode > 0) {
            float pa[8];
#pragma unroll
            for (int i = 0; i < 8; ++i) pa[i] = 0.f;
#pragma unroll
            for (int nt = 0; nt < 8; ++nt) {
                int col = nt * 16 + c;
                float2 w0 = *(const float2*)&g.wav0[col * 2];
                pa[0] += v[nt] * w0.x; pa[1] += v[nt] * w0.y;
                if (g.aMode > 1) {
                    float2 w1 = *(const float2*)&g.wav1[col * 2];
                    pa[2] += v[nt] * w1.x; pa[3] += v[nt] * w1.y;
                }
                if (g.aMode > 2) {
                    float2 w2 = *(const float2*)&g.wav2[col * 2];
                    float2 w3 = *(const float2*)&g.wav3[col * 2];
                    pa[4] += v[nt] * w2.x; pa[5] += v[nt] * w2.y;
                    pa[6] += v[nt] * w3.x; pa[7] += v[nt] * w3.y;
                }
            }
#pragma unroll
            for (int m = 8; m >= 1; m >>= 1) {
                pa[0] += __shfl_xor(pa[0], m, 64); pa[1] += __shfl_xor(pa[1], m, 64);
                pa[2] += __shfl_xor(pa[2], m, 64); pa[3] += __shfl_xor(pa[3], m, 64);
                pa[4] += __shfl_xor(pa[4], m, 64); pa[5] += __shfl_xor(pa[5], m, 64);
                pa[6] += __shfl_xor(pa[6], m, 64); pa[7] += __shfl_xor(pa[7], m, 64);
            }
            if (c == 0 && grow < g.M) {
                float* ao = &g.aOut[(size_t)grow * g.aStride];
                ao[0] = pa[0]; ao[1] = pa[1];
                if (g.aMode > 1) { ao[2] = pa[2]; ao[3] = pa[3]; }
                if (g.aMode > 2) { ao[4] = pa[4]; ao[5] = pa[5]; ao[6] = pa[6]; ao[7] = pa[7]; }
            }
        }
        if (grow < g.M) {
            unsigned short* Y = (unsigned short*)g.Y;
#pragma unroll
            for (int nt = 0; nt < 8; ++nt)
                Y[(size_t)grow * g.ldY + nt * 16 + c] = f2bf(v[nt]);
        }
    }
}

// ---------------------------------------------------------------------------
// D2a: hierarchical scan over NBINS bins (1 block, 256 threads x 211 bins).
// Produces offs (exclusive prefix, NBINS+1) and cur (scatter cursors).
// ---------------------------------------------------------------------------
__global__ __launch_bounds__(256) void k_scan(
    const int* __restrict__ bcnt, int* __restrict__ offs, int* __restrict__ cur) {
    __shared__ int sums[256];
    int t = threadIdx.x;
    const int CH = (NBINS + 255) / 256;   // 211
    int b0 = t * CH;
    int e0 = b0 + CH; if (e0 > NBINS) e0 = NBINS;
    int s = 0;
    for (int i = b0; i < e0; ++i) s += bcnt[i];
    sums[t] = s;
    __syncthreads();
    for (int off = 1; off < 256; off <<= 1) {
        int tmp = (t >= off) ? sums[t - off] : 0;
        __syncthreads();
        sums[t] += tmp;
        __syncthreads();
    }
    int run = sums[t] - s;
    for (int i = b0; i < e0; ++i) {
        int v = bcnt[i];
        offs[i] = run;
        cur[i] = run;
        run += v;
    }
    if (t == 255) offs[NBINS] = ETOT;
}

// ---------------------------------------------------------------------------
// D2b: lin0 GEMM (async-staged) blocks + direct-scatter blocks in one grid.
// Scatter: single pass, pos = atomicAdd(cur[bin]) -> esrc[pos] = src.
// ---------------------------------------------------------------------------
__global__ __launch_bounds__(256) void k_lin0_scat(
    GPair P, int gemmBlocks,
    const int* __restrict__ js_src, const int* __restrict__ js_dst,
    const int* __restrict__ sj_src, const int* __restrict__ sj_dst,
    const int* __restrict__ ss_src, const int* __restrict__ ss_dst,
    int* __restrict__ cur, int* __restrict__ esrc) {
    if (blockIdx.x < (unsigned)gemmBlocks) {
        mgemm_body<3>(P, blockIdx.x);
        return;
    }
    int t = threadIdx.x;
    int sb = blockIdx.x - gemmBlocks;
    const int CH = (ETOT + SCAT_NB - 1) / SCAT_NB;
    const int beg = sb * CH;
    const int endi = (beg + CH < ETOT) ? beg + CH : ETOT;
    if (beg >= ETOT) return;
    for (int e = beg + t; e < endi; e += 256) {
        int src, bin;
        edge_decode(e, js_src, js_dst, sj_src, sj_dst, ss_src, ss_dst, src, bin);
        int pos = atomicAdd(&cur[bin], 1);
        esrc[pos] = src;
    }
}

// ---------------------------------------------------------------------------
// Gather v5: deferred projection. Aggregates 128-dim SOURCE features.
// Quarter-wave (16 lanes) per edge, lane = 8 cols (uint4), both heads from one
// row read. Reduce via shfl_xor {16,32}.
// ---------------------------------------------------------------------------
__device__ inline void fm8(float p0, float p1, uint4 u, float a0[8], float a1[8]) {
    float x0 = __uint_as_float(u.x << 16);
    float x1 = __uint_as_float(u.x & 0xffff0000u);
    float x2 = __uint_as_float(u.y << 16);
    float x3 = __uint_as_float(u.y & 0xffff0000u);
    float x4 = __uint_as_float(u.z << 16);
    float x5 = __uint_as_float(u.z & 0xffff0000u);
    float x6 = __uint_as_float(u.w << 16);
    float x7 = __uint_as_float(u.w & 0xffff0000u);
    a0[0] += p0 * x0; a0[1] += p0 * x1; a0[2] += p0 * x2; a0[3] += p0 * x3;
    a0[4] += p0 * x4; a0[5] += p0 * x5; a0[6] += p0 * x6; a0[7] += p0 * x7;
    a1[0] += p1 * x0; a1[1] += p1 * x1; a1[2] += p1 * x2; a1[3] += p1 * x3;
    a1[4] += p1 * x4; a1[5] += p1 * x5; a1[6] += p1 * x6; a1[7] += p1 * x7;
}

__device__ inline void rel_run(
    const int* __restrict__ esrc, int beg, int end,
    const float* __restrict__ aSrc, int aShift, int aOff, float adx, float ady,
    const unsigned short* __restrict__ rows, int colOff, int g,
    float a0[8], float a1[8], float& den0, float& den1) {
    int j = beg;
    for (; j + 8 <= end; j += 8) {
        int s0 = esrc[j + g];
        int s1 = esrc[j + 4 + g];
        uint4 u0 = *(const uint4*)&rows[(unsigned)s0 * 128 + colOff];
        uint4 u1 = *(const uint4*)&rows[(unsigned)s1 * 128 + colOff];
        float2 f0 = *(const float2*)&aSrc[((unsigned)s0 << aShift) + aOff];
        float2 f1 = *(const float2*)&aSrc[((unsigned)s1 << aShift) + aOff];
        float e00 = f0.x + adx; e00 = e00 > 0.f ? e00 : 0.2f * e00;
        float e01 = f0.y + ady; e01 = e01 > 0.f ? e01 : 0.2f * e01;
        float e10 = f1.x + adx; e10 = e10 > 0.f ? e10 : 0.2f * e10;
        float e11 = f1.y + ady; e11 = e11 > 0.f ? e11 : 0.2f * e11;
        float p00 = __expf(e00), p01 = __expf(e01);
        float p10 = __expf(e10), p11 = __expf(e11);
        fm8(p00, p01, u0, a0, a1);
        fm8(p10, p11, u1, a0, a1);
        den0 += p00 + p10; den1 += p01 + p11;
    }
    for (; j < end; j += 4) {
        int e = j + g;
        bool ok = e < end;
        int s = esrc[ok ? e : j];
        uint4 u = *(const uint4*)&rows[(unsigned)s * 128 + colOff];
        float2 f = *(const float2*)&aSrc[((unsigned)s << aShift) + aOff];
        float e0 = f.x + adx; e0 = e0 > 0.f ? e0 : 0.2f * e0;
        float e1 = f.y + ady; e1 = e1 > 0.f ? e1 : 0.2f * e1;
        float p0 = ok ? __expf(e0) : 0.f;
        float p1 = ok ? __expf(e1) : 0.f;
        fm8(p0, p1, u, a0, a1);
        den0 += p0; den1 += p1;
    }
}

__device__ inline void store8(unsigned short* dst, const float v[8]) {
    uint4 o;
    o.x = (unsigned)f2bf(v[0]) | ((unsigned)f2bf(v[1]) << 16);
    o.y = (unsigned)f2bf(v[2]) | ((unsigned)f2bf(v[3]) << 16);
    o.z = (unsigned)f2bf(v[4]) | ((unsigned)f2bf(v[5]) << 16);
    o.w = (unsigned)f2bf(v[6]) | ((unsigned)f2bf(v[7]) << 16);
    *(uint4*)dst = o;
}

__device__ inline void finish_store(float a0[8], float a1[8], float den0, float den1,
                                    int lane, unsigned short* base) {
    float d0 = den0; d0 += __shfl_xor(d0, 16, 64); d0 += __shfl_xor(d0, 32, 64);
    float d1 = den1; d1 += __shfl_xor(d1, 16, 64); d1 += __shfl_xor(d1, 32, 64);
    float s0 = 1.f / (d0 + 1e-16f), s1 = 1.f / (d1 + 1e-16f);
    float o0[8], o1[8];
#pragma unroll
    for (int i = 0; i < 8; ++i) {
        float t0 = a0[i]; t0 += __shfl_xor(t0, 16, 64); t0 += __shfl_xor(t0, 32, 64);
        float t1 = a1[i]; t1 += __shfl_xor(t1, 16, 64); t1 += __shfl_xor(t1, 32, 64);
        o0[i] = t0 * s0; o1[i] = t1 * s1;
    }
    if ((lane >> 4) == 0) {
        store8(base, o0);
        store8(base + 128, o1);
    }
}

__global__ __launch_bounds__(256) void k_gather_all(
    const int* __restrict__ offs, const int* __restrict__ esrc,
    const float* __restrict__ aJ, const float* __restrict__ aS,
    const unsigned short* __restrict__ rowsJ,   // job src rows (ld 128)
    const unsigned short* __restrict__ rowsS,   // skill src rows (ld 128)
    unsigned short* __restrict__ aggS,          // [NS][512]: jsH0|jsH1|ssH0|ssH1
    unsigned short* __restrict__ aggJ,          // [NJ][256]: sjH0|sjH1
    int jobOnly) {
    int wave = threadIdx.x >> 6, lane = threadIdx.x & 63;
    int idx = blockIdx.x * 4 + wave;
    int g = lane >> 4, cl = lane & 15;
    int colOff = cl * 8;

    float a0[8], a1[8], den0, den1;

    if (jobOnly) {
        if (idx >= NJ) return;
        int d = idx;
#pragma unroll
        for (int i = 0; i < 8; ++i) { a0[i] = 0.f; a1[i] = 0.f; }
        den0 = den1 = 0.f;
        int bb = NS + d;
        float2 ad = *(const float2*)&aJ[(unsigned)d * 4 + 2];
        rel_run(esrc, offs[bb], offs[bb + 1], aS, 3, 4, ad.x, ad.y, rowsS, colOff, g, a0, a1, den0, den1);
        finish_store(a0, a1, den0, den1, lane, &aggJ[(size_t)d * 256 + colOff]);
        return;
    }
    if (idx < NS) {
        int d = idx;
#pragma unroll
        for (int i = 0; i < 8; ++i) { a0[i] = 0.f; a1[i] = 0.f; }
        den0 = den1 = 0.f;
        float2 adA = *(const float2*)&aS[(unsigned)d * 8 + 2];
        rel_run(esrc, offs[d], offs[d + 1], aJ, 2, 0, adA.x, adA.y, rowsJ, colOff, g, a0, a1, den0, den1);
        finish_store(a0, a1, den0, den1, lane, &aggS[(size_t)d * 512 + colOff]);
#pragma unroll
        for (int i = 0; i < 8; ++i) { a0[i] = 0.f; a1[i] = 0.f; }
        den0 = den1 = 0.f;
        int bb = NS + NJ + d;
        float2 adB = *(const float2*)&aS[(unsigned)d * 8 + 6];
        rel_run(esrc, offs[bb], offs[bb + 1], aS, 3, 0, adB.x, adB.y, rowsS, colOff, g, a0, a1, den0, den1);
        finish_store(a0, a1, den0, den1, lane, &aggS[(size_t)d * 512 + 256 + colOff]);
    } else if (idx < NS + NJ) {
        int d = idx - NS;
#pragma unroll
        for (int i = 0; i < 8; ++i) { a0[i] = 0.f; a1[i] = 0.f; }
        den0 = den1 = 0.f;
        int bb = NS + d;
        float2 ad = *(const float2*)&aJ[(unsigned)d * 4 + 2];
        rel_run(esrc, offs[bb], offs[bb + 1], aS, 3, 4, ad.x, ad.y, rowsS, colOff, g, a0, a1, den0, den1);
        finish_store(a0, a1, den0, den1, lane, &aggJ[(size_t)d * 256 + colOff]);
    }
}

// ---------------------------------------------------------------------------
// D6: two-stage fused GEMM, single-pass stage1. Both 128-col output halves of
// stage1 are computed in ONE K-pass (Bl holds 256 weight rows; acc0/acc1 in
// registers). Stage2 consumes each half from Y1l[4] in its K-slice.
// LDS = Al(5K)+Bl(20.5K)+Y1l(20.5K) = 46KB -> 3 blocks/CU.
// ---------------------------------------------------------------------------
struct FJob {
    const unsigned short* X; int K1; int M;
    const unsigned short* Wt1; const float* bias1;
    const unsigned short* Wt2; const float* bias2;
    const float* wa; float* aOut; int aStride;
    unsigned short* Y2;                          // nullable; ld 128
};
struct FPair { FJob a; FJob b; int blocksA; };

__global__ __launch_bounds__(256) void k_fused2(FPair P) {
    int mb = blockIdx.x;
    FJob g = (mb < P.blocksA) ? P.a : P.b;
    if (mb >= P.blocksA) mb -= P.blocksA;
    const int row0 = mb * 64;
    const int K1 = g.K1;

    __shared__ __align__(16) unsigned short Al[64][40];
    __shared__ __align__(16) unsigned short Bl[256][40];
    __shared__ __align__(16) unsigned short Y1l[4][64][40];
    const int t = threadIdx.x;
    const int wave = t >> 6, lane = t & 63;
    const int q = lane >> 4, c = lane & 15;

    f4_t acc0[8], acc1[8], acc2[8];
#pragma unroll
    for (int nt = 0; nt < 8; ++nt) {
        acc0[nt] = (f4_t){0.f, 0.f, 0.f, 0.f};
        acc1[nt] = (f4_t){0.f, 0.f, 0.f, 0.f};
        acc2[nt] = (f4_t){0.f, 0.f, 0.f, 0.f};
    }

    // stage1: single K-pass, both column halves
    for (int k0 = 0; k0 < K1; k0 += 32) {
#pragma unroll
        for (int it = 0; it < 5; ++it) {
            int idx = t + it * 256;
            int r = idx >> 2, cc = (idx & 3) * 8;
            if (r < 64) {
                int gr = row0 + r;
                uint4 va = (gr < g.M) ? *(const uint4*)&g.X[(size_t)gr * K1 + k0 + cc]
                                      : make_uint4(0u, 0u, 0u, 0u);
                *(uint4*)&Al[r][cc] = va;
            } else {
                int br = r - 64;   // 0..255
                *(uint4*)&Bl[br][cc] = *(const uint4*)&g.Wt1[(size_t)br * K1 + k0 + cc];
            }
        }
        __syncthreads();
        bf8_t af = *(const bf8_t*)&Al[wave * 16 + c][q * 8];
#pragma unroll
        for (int nt = 0; nt < 8; ++nt) {
            bf8_t b0 = *(const bf8_t*)&Bl[nt * 16 + c][q * 8];
            acc0[nt] = __builtin_amdgcn_mfma_f32_16x16x32_bf16(af, b0, acc0[nt], 0, 0, 0);
            bf8_t b1 = *(const bf8_t*)&Bl[128 + nt * 16 + c][q * 8];
            acc1[nt] = __builtin_amdgcn_mfma_f32_16x16x32_bf16(af, b1, acc1[nt], 0, 0, 0);
        }
        __syncthreads();
    }

    // per half: park in Y1l, run stage2 K-slice
#pragma unroll
    for (int np = 0; np < 2; ++np) {
        float bcol[8];
#pragma unroll
        for (int nt = 0; nt < 8; ++nt) bcol[nt] = g.bias1[np * 128 + nt * 16 + c];
#pragma unroll
        for (int r = 0; r < 4; ++r) {
            int row = wave * 16 + q * 4 + r;
#pragma unroll
            for (int nt = 0; nt < 8; ++nt) {
                float vv = (np ? acc1[nt][r] : acc0[nt][r]) + bcol[nt];
                Y1l[nt >> 1][row][(nt & 1) * 16 + c] = f2bf(vv);
            }
        }
        __syncthreads();
        for (int k0 = 0; k0 < 128; k0 += 32) {
#pragma unroll
            for (int it = 0; it < 2; ++it) {
                int idx = t + it * 256;
                int br = idx >> 2, cc = (idx & 3) * 8;
                *(uint4*)&Bl[br][cc] = *(const uint4*)&g.Wt2[(size_t)br * 256 + np * 128 + k0 + cc];
            }
            __syncthreads();
            bf8_t af = *(const bf8_t*)&Y1l[k0 >> 5][wave * 16 + c][q * 8];
#pragma unroll
            for (int nt = 0; nt < 8; ++nt) {
                bf8_t bfr = *(const bf8_t*)&Bl[nt * 16 + c][q * 8];
                acc2[nt] = __builtin_amdgcn_mfma_f32_16x16x32_bf16(af, bfr, acc2[nt], 0, 0, 0);
            }
            __syncthreads();
        }
    }

    float b2[8];
#pragma unroll
    for (int nt = 0; nt < 8; ++nt) b2[nt] = g.bias2[nt * 16 + c];
#pragma unroll
    for (int r = 0; r < 4; ++r) {
        int grow = row0 + wave * 16 + q * 4 + r;
        float v[8];
#pragma unroll
        for (int nt = 0; nt < 8; ++nt) v[nt] = fmaxf(acc2[nt][r] + b2[nt], 0.f);
        if (g.wa) {
            float pa0 = 0.f, pa1 = 0.f;
#pragma unroll
            for (int nt = 0; nt < 8; ++nt) {
                float2 w0 = *(const float2*)&g.wa[(nt * 16 + c) * 2];
                pa0 += v[nt] * w0.x; pa1 += v[nt] * w0.y;
            }
#pragma unroll
            for (int m = 8; m >= 1; m >>= 1) {
                pa0 += __shfl_xor(pa0, m, 64);
                pa1 += __shfl_xor(pa1, m, 64);
            }
            if (c == 0 && grow < g.M) {
                g.aOut[(size_t)grow * g.aStride + 0] = pa0;
                g.aOut[(size_t)grow * g.aStride + 1] = pa1;
            }
        }
        if (g.Y2 && grow < g.M) {
#pragma unroll
            for (int nt = 0; nt < 8; ++nt)
                g.Y2[(size_t)grow * 128 + nt * 16 + c] = f2bf(v[nt]);
        }
    }
}

// ---------------------------------------------------------------------------
// D8: three-stage fused GEMM, single-pass stage1 (same restructure as
// k_fused2); Yl reused for stage2 output (stage3 input). 46KB LDS.
// ---------------------------------------------------------------------------
struct F3 {
    const unsigned short* X; int M;
    const unsigned short* Wt1; const float* bias1;
    const unsigned short* Wt2; const float* bias2;
    const unsigned short* Wt3; const float* bias3;
    const float* qv; float* sc; float* Y;
};

__global__ __launch_bounds__(256) void k_fused3(F3 g) {
    int mb = blockIdx.x;
    const int row0 = mb * 64;
    __shared__ __align__(16) unsigned short Al[64][40];
    __shared__ __align__(16) unsigned short Bl[256][40];
    __shared__ __align__(16) unsigned short Yl[4][64][40];
    const int t = threadIdx.x;
    const int wave = t >> 6, lane = t & 63;
    const int q = lane >> 4, c = lane & 15;

    f4_t acc0[8], acc1[8], acc2[8];
#pragma unroll
    for (int nt = 0; nt < 8; ++nt) {
        acc0[nt] = (f4_t){0.f, 0.f, 0.f, 0.f};
        acc1[nt] = (f4_t){0.f, 0.f, 0.f, 0.f};
        acc2[nt] = (f4_t){0.f, 0.f, 0.f, 0.f};
    }

    // stage1: single K-pass over 256, both column halves
    for (int k0 = 0; k0 < 256; k0 += 32) {
#pragma unroll
        for (int it = 0; it < 5; ++it) {
            int idx = t + it * 256;
            int r = idx >> 2, cc = (idx & 3) * 8;
            if (r < 64) {
                int gr = row0 + r;
                uint4 va = (gr < g.M) ? *(const uint4*)&g.X[(size_t)gr * 256 + k0 + cc]
                                      : make_uint4(0u, 0u, 0u, 0u);
                *(uint4*)&Al[r][cc] = va;
            } else {
                int br = r - 64;
                *(uint4*)&Bl[br][cc] = *(const uint4*)&g.Wt1[(size_t)br * 256 + k0 + cc];
            }
        }
        __syncthreads();
        bf8_t af = *(const bf8_t*)&Al[wave * 16 + c][q * 8];
#pragma unroll
        for (int nt = 0; nt < 8; ++nt) {
            bf8_t b0 = *(const bf8_t*)&Bl[nt * 16 + c][q * 8];
            acc0[nt] = __builtin_amdgcn_mfma_f32_16x16x32_bf16(af, b0, acc0[nt], 0, 0, 0);
            bf8_t b1 = *(const bf8_t*)&Bl[128 + nt * 16 + c][q * 8];
            acc1[nt] = __builtin_amdgcn_mfma_f32_16x16x32_bf16(af, b1, acc1[nt], 0, 0, 0);
        }
        __syncthreads();
    }

    // per half: park in Yl, run stage2 K-slice
#pragma unroll
    for (int np = 0; np < 2; ++np) {
        float bcol[8];
#pragma unroll
        for (int nt = 0; nt < 8; ++nt) bcol[nt] = g.bias1[np * 128 + nt * 16 + c];
#pragma unroll
        for (int r = 0; r < 4; ++r) {
            int row = wave * 16 + q * 4 + r;
#pragma unroll
            for (int nt = 0; nt < 8; ++nt) {
                float vv = (np ? acc1[nt][r] : acc0[nt][r]) + bcol[nt];
                Yl[nt >> 1][row][(nt & 1) * 16 + c] = f2bf(vv);
            }
        }
        __syncthreads();
        for (int k0 = 0; k0 < 128; k0 += 32) {
#pragma unroll
            for (int it = 0; it < 2; ++it) {
                int idx = t + it * 256;
                int br = idx >> 2, cc = (idx & 3) * 8;
                *(uint4*)&Bl[br][cc] = *(const uint4*)&g.Wt2[(size_t)br * 256 + np * 128 + k0 + cc];
            }
            __syncthreads();
            bf8_t af = *(const bf8_t*)&Yl[k0 >> 5][wave * 16 + c][q * 8];
#pragma unroll
            for (int nt = 0; nt < 8; ++nt) {
                bf8_t bfr = *(const bf8_t*)&Bl[nt * 16 + c][q * 8];
                acc2[nt] = __builtin_amdgcn_mfma_f32_16x16x32_bf16(af, bfr, acc2[nt], 0, 0, 0);
            }
            __syncthreads();
        }
    }

    // stage2 epilogue: bias + relu -> Yl (prior contents fully consumed)
    {
        float b2[8];
#pragma unroll
        for (int nt = 0; nt < 8; ++nt) b2[nt] = g.bias2[nt * 16 + c];
#pragma unroll
        for (int r = 0; r < 4; ++r) {
            int row = wave * 16 + q * 4 + r;
#pragma unroll
            for (int nt = 0; nt < 8; ++nt)
                Yl[nt >> 1][row][(nt & 1) * 16 + c] = f2bf(fmaxf(acc2[nt][r] + b2[nt], 0.f));
        }
        __syncthreads();
    }

    // stage3: 128 -> 128, f32 out + scores
    f4_t acc3[8];
#pragma unroll
    for (int nt = 0; nt < 8; ++nt) acc3[nt] = (f4_t){0.f, 0.f, 0.f, 0.f};
    for (int k0 = 0; k0 < 128; k0 += 32) {
#pragma unroll
        for (int it = 0; it < 2; ++it) {
            int idx = t + it * 256;
            int br = idx >> 2, cc = (idx & 3) * 8;
            *(uint4*)&Bl[br][cc] = *(const uint4*)&g.Wt3[(size_t)br * 128 + k0 + cc];
        }
        __syncthreads();
        bf8_t af = *(const bf8_t*)&Yl[k0 >> 5][wave * 16 + c][q * 8];
#pragma unroll
        for (int nt = 0; nt < 8; ++nt) {
            bf8_t bfr = *(const bf8_t*)&Bl[nt * 16 + c][q * 8];
            acc3[nt] = __builtin_amdgcn_mfma_f32_16x16x32_bf16(af, bfr, acc3[nt], 0, 0, 0);
        }
        __syncthreads();
    }
    float b3[8], qcol[8];
#pragma unroll
    for (int nt = 0; nt < 8; ++nt) {
        b3[nt] = g.bias3[nt * 16 + c];
        qcol[nt] = g.qv[nt * 16 + c];
    }
#pragma unroll
    for (int r = 0; r < 4; ++r) {
        int grow = row0 + wave * 16 + q * 4 + r;
        float v[8];
#pragma unroll
        for (int nt = 0; nt < 8; ++nt) v[nt] = acc3[nt][r] + b3[nt];
        float part = 0.f;
#pragma unroll
        for (int nt = 0; nt < 8; ++nt) part += v[nt] * qcol[nt];
#pragma unroll
        for (int m = 8; m >= 1; m >>= 1) part += __shfl_xor(part, m, 64);
        if (grow < g.M) {
            if (c == 0) g.sc[grow] = part;
#pragma unroll
            for (int nt = 0; nt < 8; ++nt)
                g.Y[(size_t)grow * 128 + nt * 16 + c] = v[nt];
        }
    }
}

// ---------------------------------------------------------------------------
extern "C" void kernel_launch(void* const* d_in, const int* in_sizes, int n_in,
                              void* d_out, int out_size, void* d_ws, size_t ws_size,
                              hipStream_t stream) {
    const float* x_job   = (const float*)d_in[0];
    const float* x_skill = (const float*)d_in[1];
    const int* js_src = (const int*)d_in[2];
    const int* js_dst = (const int*)d_in[3];
    const int* sj_src = (const int*)d_in[4];
    const int* sj_dst = (const int*)d_in[5];
    const int* ss_src = (const int*)d_in[6];
    const int* ss_dst = (const int*)d_in[7];
    const float* query    = (const float*)d_in[8];
    const float* W0_job   = (const float*)d_in[9];
    const float* b0_job   = (const float*)d_in[10];
    const float* g0_job   = (const float*)d_in[11];
    const float* be0_job  = (const float*)d_in[12];
    const float* W0_skill = (const float*)d_in[13];
    const float* b0_skill = (const float*)d_in[14];
    const float* g0_skill = (const float*)d_in[15];
    const float* be0_skill= (const float*)d_in[16];
    const float* gat_Ws = (const float*)d_in[17];
    const float* gat_Wd = (const float*)d_in[18];
    const float* gat_as = (const float*)d_in[19];
    const float* gat_ad = (const float*)d_in[20];
    const float* gat_b  = (const float*)d_in[21];
    const float* inter_W = (const float*)d_in[22];
    const float* inter_b = (const float*)d_in[23];
    const float* Wjf = (const float*)d_in[24];
    const float* bjf = (const float*)d_in[25];
    const float* Wq  = (const float*)d_in[26];
    const float* bq  = (const float*)d_in[27];

    char* w = (char*)d_ws;
    auto alloc = [&](size_t bytes) -> void* {
        void* p = (void*)w;
        w += (bytes + 255) & ~(size_t)255;
        return p;
    };
    u16* xj   = (u16*)alloc((size_t)NJ * 128 * 2);
    u16* xs   = (u16*)alloc((size_t)NS * 128 * 2);
    u16* xs1  = (u16*)alloc((size_t)NS * 128 * 2);
    u16* aggJ  = (u16*)alloc((size_t)NJ * 256 * 2);
    u16* aggJ1 = (u16*)alloc((size_t)NJ * 256 * 2);
    u16* aggS  = (u16*)alloc((size_t)NS * 512 * 2);
    u16* WtW0j = (u16*)alloc((size_t)SBERT * 128 * 2);
    u16* WtW0s = (u16*)alloc((size_t)SBERT * 128 * 2);
    u16* WsS1  = (u16*)alloc((size_t)256 * 512 * 2);
    u16* WsJ0  = (u16*)alloc((size_t)256 * 256 * 2);
    u16* WsJ1  = (u16*)alloc((size_t)256 * 256 * 2);
    u16* WtI00 = (u16*)alloc((size_t)128 * 256 * 2);
    u16* WtI01 = (u16*)alloc((size_t)128 * 256 * 2);
    u16* WtI10 = (u16*)alloc((size_t)128 * 256 * 2);
    u16* WtJf  = (u16*)alloc((size_t)128 * 128 * 2);
    float* gbS = (float*)alloc(256 * 4);
    float* aJ = (float*)alloc((size_t)NJ * 4 * 4);
    float* aS = (float*)alloc((size_t)NS * 8 * 4);
    float* wsa = (float*)alloc(6 * 256 * 4);
    float* wda = (float*)alloc(6 * 256 * 4);
    int* bcnt = (int*)alloc((size_t)NBINS * 4);
    int* offs = (int*)alloc((size_t)(NBINS + 1) * 4);
    int* curb = (int*)alloc((size_t)NBINS * 4);
    int* esrc = (int*)alloc((size_t)ETOT * 4);

    float* out = (float*)d_out;
    float* scores  = out;
    float* job_emb = out + NJ;
    float* qv      = out + NJ + (size_t)NJ * 128;

    const int mbJ = cdiv(NJ, 64);   // 469
    const int mbS = cdiv(NS, 64);   // 188
    const int gemmB = mbJ + mbS;    // 657

    // M0: zero bin counters + structured weight buffers (block layouts)
    hipMemsetAsync(bcnt, 0, (size_t)NBINS * 4, stream);
    hipMemsetAsync(WsS1, 0, (size_t)256 * 512 * 2, stream);
    hipMemsetAsync(WsJ0, 0, (size_t)256 * 256 * 2, stream);
    hipMemsetAsync(WsJ1, 0, (size_t)256 * 256 * 2, stream);

    // D1: prep (weight casts/structured layouts + wa + qvec + gbS + hist)
    {
        const size_t WS = (size_t)128 * 256;
        const size_t IW = (size_t)256 * 128;
        PrepArgs A;
        A.m[0]  = {W0_job,   WtW0j, SBERT, 128, 128, SBERT};
        A.m[1]  = {W0_skill, WtW0s, SBERT, 128, 128, SBERT};
        // WsS1 (256x512): [n<128,k<128]=Ws00[:,:128]; [n>=128,k 128..256)=Ws00[:,128:]
        //                 [n<128,k 256..384)=Ws02[:,:128]; [n>=128,k 384..512)=Ws02[:,128:]
        A.m[2]  = {gat_Ws + 0 * WS,       WsS1,                       128, 128, 256, 512};
        A.m[3]  = {gat_Ws + 0 * WS + 128, WsS1 + 128 * 512 + 128,     128, 128, 256, 512};
        A.m[4]  = {gat_Ws + 2 * WS,       WsS1 + 256,                 128, 128, 256, 512};
        A.m[5]  = {gat_Ws + 2 * WS + 128, WsS1 + 128 * 512 + 384,     128, 128, 256, 512};
        // WsJ0 (256x256): block-diag from Ws01
        A.m[6]  = {gat_Ws + 1 * WS,       WsJ0,                       128, 128, 256, 256};
        A.m[7]  = {gat_Ws + 1 * WS + 128, WsJ0 + 128 * 256 + 128,     128, 128, 256, 256};
        // WsJ1 (256x256): block-diag from Ws11
        A.m[8]  = {gat_Ws + 4 * WS,       WsJ1,                       128, 128, 256, 256};
        A.m[9]  = {gat_Ws + 4 * WS + 128, WsJ1 + 128 * 256 + 128,     128, 128, 256, 256};
        A.m[10] = {inter_W + 0 * IW, WtI00, 256, 128, 128, 256};
        A.m[11] = {inter_W + 1 * IW, WtI01, 256, 128, 128, 256};
        A.m[12] = {inter_W + 2 * IW, WtI10, 256, 128, 128, 256};
        A.m[13] = {Wjf, WtJf, 128, 128, 128, 128};
        A.Ws = gat_Ws; A.as_ = gat_as; A.Wd = gat_Wd; A.ad_ = gat_ad;
        A.wsa = wsa; A.wda = wda; A.bcnt = bcnt;
        A.query = query; A.Wq = Wq; A.bq = bq; A.qv = qv;
        A.gat_b = gat_b; A.gbS = gbS;
        A.js_src = js_src; A.js_dst = js_dst;
        A.sj_src = sj_src; A.sj_dst = sj_dst;
        A.ss_src = ss_src; A.ss_dst = ss_dst;
        k_prep<<<PREP_HIST + HIST_NB, 256, 0, stream>>>(A);
    }

    // D2a: bin scan (1 block, hierarchical)
    k_scan<<<1, 256, 0, stream>>>(bcnt, offs, curb);

    // D2b: lin0 GEMM + direct-scatter blocks merged
    {
        GPair P;
        P.a = {x_job, WtW0j, b0_job, g0_job, be0_job, xj, NJ, SBERT, 128, 128, 1,
               nullptr, nullptr, 2, wsa + 0, wda + 256, nullptr, nullptr, aJ, 4};
        P.b = {x_skill, WtW0s, b0_skill, g0_skill, be0_skill, xs, NS, SBERT, 128, 128, 1,
               nullptr, nullptr, 4, wsa + 2 * 256, wda + 0, wsa + 1 * 256, wda + 2 * 256, aS, 8};
        P.blocksA = mbJ;
        k_lin0_scat<<<gemmB + SCAT_NB, 256, 0, stream>>>(
            P, gemmB, js_src, js_dst, sj_src, sj_dst, ss_src, ss_dst, curb, esrc);
    }

    // D5: gather l0 — aggregate 128-dim source features (both heads)
    k_gather_all<<<cdiv(NS + NJ, 4), 256, 0, stream>>>(
        offs, esrc, aJ, aS, xj, xs, aggS, aggJ, 0);

    // D6: fused Ws-proj + inter (relu) + alpha-l1. Job: no Y2 store needed.
    {
        FPair P;
        P.a = {aggJ, 256, NJ, WsJ0, gat_b + 256, WtI00, inter_b + 0,
               wda + 4 * 256, aJ + 2, 4, nullptr};
        P.b = {aggS, 512, NS, WsS1, gbS, WtI01, inter_b + 128,
               wsa + 4 * 256, aS + 4, 8, xs1};
        P.blocksA = mbJ;
        k_fused2<<<gemmB, 256, 0, stream>>>(P);
    }

    // D7: gather l1 (job dsts only; srcs are xs1, 3MB working set)
    k_gather_all<<<cdiv(NJ, 4), 256, 0, stream>>>(
        offs, esrc, aJ, aS, nullptr, xs1, nullptr, aggJ1, 1);

    // D8: fused Ws-proj + inter(relu) + final projection + scores
    {
        F3 g3;
        g3.X = aggJ1; g3.M = NJ;
        g3.Wt1 = WsJ1; g3.bias1 = gat_b + 4 * 256;
        g3.Wt2 = WtI10; g3.bias2 = inter_b + 2 * 128;
        g3.Wt3 = WtJf; g3.bias3 = bjf;
        g3.qv = qv; g3.sc = scores; g3.Y = job_emb;
        k_fused3<<<mbJ, 256, 0, stream>>>(g3);
    }
}

// Round 12
// 414.685 us; speedup vs baseline: 1.1806x; 1.1806x over previous
//
#include <hip/hip_runtime.h>
#include <hip/hip_bf16.h>
#include <math.h>

#define NJ 30000
#define NS 12000
#define E_JS 300000
#define E_SJ 300000
#define E_SS 150000
#define ETOT (E_JS + E_SJ + E_SS + NS)   // 762000 incl. ss self loops
#define NBINS (NS + NJ + NS)             // 54000 combined dst bins
#define SBERT 384
#define HIST_NB 512
#define SCAT_NB 480
#define CAST_MATS 14
#define CAST_BPM 48
#define PREP_CAST (CAST_MATS * CAST_BPM)          // 672
#define PREP_WA   (PREP_CAST + 192)               // 864 (quarter-wave per output)
#define PREP_QV   PREP_WA                         // 864
#define PREP_GB   (PREP_QV + 1)                   // 865
#define PREP_HIST (PREP_GB + 1)                   // 866

static inline int cdiv(int a, int b) { return (a + b - 1) / b; }

typedef __attribute__((ext_vector_type(8))) short bf8_t;
typedef __attribute__((ext_vector_type(4))) float f4_t;
typedef unsigned short u16;

__device__ inline float bf2f(unsigned short u) {
    union { unsigned int i; float f; } z; z.i = ((unsigned int)u) << 16; return z.f;
}
__device__ inline unsigned short f2bf(float f) {
    unsigned int x = __float_as_uint(f);
    unsigned int r = (x + 0x7fffu + ((x >> 16) & 1u)) >> 16;   // RNE
    return (unsigned short)r;
}

// ---------------------------------------------------------------------------
// edge decode; bin layout: [0,NS) js | [NS,NS+NJ) sj | [NS+NJ,NBINS) ss+loops
// ---------------------------------------------------------------------------
__device__ inline void edge_decode(int e, const int* js_src, const int* js_dst,
                                   const int* sj_src, const int* sj_dst,
                                   const int* ss_src, const int* ss_dst,
                                   int& src, int& bin) {
    if (e < E_JS) { src = js_src[e]; bin = js_dst[e]; }
    else if (e < E_JS + E_SJ) { int i = e - E_JS; src = sj_src[i]; bin = NS + sj_dst[i]; }
    else if (e < E_JS + E_SJ + E_SS) { int i = e - E_JS - E_SJ; src = ss_src[i]; bin = NS + NJ + ss_dst[i]; }
    else { int i = e - E_JS - E_SJ - E_SS; src = i; bin = NS + NJ + i; }
}

// ---------------------------------------------------------------------------
// D1 k_prep: castT [0,672) | wa [672,864) | qvec [864] | gbS [865] | hist...
// bcnt (NBINS ints) / WsS1 / WsJ0 / WsJ1 zeroed by hipMemsetAsync first.
// hist: DIRECT per-bin global atomics (counting-sort CSR).
// ---------------------------------------------------------------------------
struct CastT { const float* src; unsigned short* dst; int K; int N; int srcLd; int dstLd; };
struct PrepArgs {
    CastT m[CAST_MATS];
    const float* Ws; const float* as_; const float* Wd; const float* ad_;
    float* wsa; float* wda; int* bcnt;
    const float* query; const float* Wq; const float* bq; float* qv;
    const float* gat_b; float* gbS;
    const int* js_src; const int* js_dst;
    const int* sj_src; const int* sj_dst;
    const int* ss_src; const int* ss_dst;
};

__global__ __launch_bounds__(256) void k_prep(PrepArgs A) {
    __shared__ float ldt[32][33];
    int b = blockIdx.x;
    if (b < PREP_CAST) {
        int mi = b / CAST_BPM, bx = b % CAST_BPM;
        CastT cm = A.m[mi];
        int tilesN = cm.N >> 5;
        int total = (cm.K >> 5) * tilesN;
        if (bx >= total) return;
        int tk = bx / tilesN, tn = bx % tilesN;
        int k0 = tk * 32, n0 = tn * 32;
        int col = threadIdx.x & 31;
        int row0 = threadIdx.x >> 5;
#pragma unroll
        for (int r = 0; r < 4; ++r) {
            int kk = row0 + r * 8;
            ldt[kk][col] = cm.src[(size_t)(k0 + kk) * cm.srcLd + n0 + col];
        }
        __syncthreads();
#pragma unroll
        for (int r = 0; r < 4; ++r) {
            int nn = row0 + r * 8;
            cm.dst[(size_t)(n0 + nn) * cm.dstLd + k0 + col] = f2bf(ldt[col][nn]);
        }
    } else if (b < PREP_WA) {
        int qw = ((b - PREP_CAST) * 256 + threadIdx.x) >> 4;   // quarter-wave id
        int cl = threadIdx.x & 15;
        if (qw < 2 * 1536) {
            int which = qw / 1536;
            int r = qw % 1536;
            int lr = r / 256;
            int kh = r % 256;
            int k = kh / 2, h = kh % 2;
            const float* W = which ? A.Wd : A.Ws;
            const float* a = which ? A.ad_ : A.as_;
            const float* wrow = W + ((size_t)(lr * 128 + k)) * 256 + h * 128 + cl * 8;
            const float* arow = a + (size_t)(lr * 2 + h) * 128 + cl * 8;
            float4 w0 = *(const float4*)wrow, w1 = *(const float4*)(wrow + 4);
            float4 a0 = *(const float4*)arow, a1 = *(const float4*)(arow + 4);
            float acc = w0.x * a0.x + w0.y * a0.y + w0.z * a0.z + w0.w * a0.w
                      + w1.x * a1.x + w1.y * a1.y + w1.z * a1.z + w1.w * a1.w;
            acc += __shfl_xor(acc, 1, 64);
            acc += __shfl_xor(acc, 2, 64);
            acc += __shfl_xor(acc, 4, 64);
            acc += __shfl_xor(acc, 8, 64);
            if (cl == 0) (which ? A.wda : A.wsa)[lr * 256 + k * 2 + h] = acc;
        }
    } else if (b == PREP_QV) {
        int c = threadIdx.x;
        if (c < 128) {
            float acc = A.bq[c];
            for (int k = 0; k < SBERT; ++k) acc += A.query[k] * A.Wq[(size_t)k * 128 + c];
            A.qv[c] = acc;
        }
    } else if (b == PREP_GB) {
        int c = threadIdx.x;
        if (c < 256) A.gbS[c] = A.gat_b[c] + A.gat_b[512 + c];   // gb(0,0)+gb(0,2)
    } else {
        int hb = b - PREP_HIST;
        for (int e = hb * 256 + threadIdx.x; e < ETOT; e += HIST_NB * 256) {
            int src, bin;
            edge_decode(e, A.js_src, A.js_dst, A.sj_src, A.sj_dst, A.ss_src, A.ss_dst, src, bin);
            atomicAdd(&A.bcnt[bin], 1);
        }
    }
}

// ---------------------------------------------------------------------------
// MFMA GEMM body for D2 lin0 (fp32 X, K=384). BM=64, 4 waves x (16m x 128n).
// Round-6 structure (best measured): global_load_lds width-16 into linear LDS,
// XOR-block-swizzled on the GLOBAL source; reads apply the same swizzle.
// ONE barrier per K-step; stage for tile k+1 issued after the barrier.
// EPI 3: +bias,LN,relu->bf16, with alpha epilogue (aMode pairs).
// ---------------------------------------------------------------------------
struct GJob {
    const void* X; const unsigned short* Wt;
    const float* bias; const float* gamma; const float* beta;
    void* Y; int M; int K; int N; int ldY; int srcf32;
    const float* qv; float* sc;
    int aMode = 0;
    const float* wav0 = nullptr; const float* wav1 = nullptr;
    const float* wav2 = nullptr; const float* wav3 = nullptr;
    float* aOut = nullptr; int aStride = 0;
};
struct GPair { GJob a; GJob b; int blocksA; };

template <int EPI>
__device__ void mgemm_body(const GPair& P, int bx) {
    int mb = bx;
    GJob g = (mb < P.blocksA) ? P.a : P.b;
    if (mb >= P.blocksA) mb -= P.blocksA;
    const int row0 = mb * 64;

    __shared__ __align__(16) float As[2][64][32];           // 16 KB
    __shared__ __align__(16) unsigned short Bs[2][128][32]; // 16 KB
    const int t = threadIdx.x;
    const int wave = t >> 6, lane = t & 63;
    const int q = lane >> 4, c = lane & 15;
    const int K = g.K;
    const float* Xf = (const float*)g.X;

    f4_t acc[8];
#pragma unroll
    for (int nt = 0; nt < 8; ++nt) acc[nt] = (f4_t){0.f, 0.f, 0.f, 0.f};

    auto STAGE = [&](int cur, int k0) {
#pragma unroll
        for (int i = 0; i < 2; ++i) {
            int bi = i * 256 + t;
            int row = bi >> 3, b = bi & 7;
            int ra = row0 + row; ra = (ra < g.M) ? ra : (g.M - 1);
            const float* gsrc = Xf + (size_t)ra * K + k0 + ((b ^ (row & 7)) << 2);
            __builtin_amdgcn_global_load_lds(
                (__attribute__((address_space(1))) void*)gsrc,
                (__attribute__((address_space(3))) void*)((char*)&As[cur][0][0] + ((i * 4 + wave) << 10)),
                16, 0, 0);
        }
#pragma unroll
        for (int i = 0; i < 2; ++i) {
            int bi = i * 256 + t;
            int row = bi >> 2, b = bi & 3;
            const unsigned short* gsrc = g.Wt + (size_t)row * K + k0 + ((b ^ ((row >> 1) & 3)) << 3);
            __builtin_amdgcn_global_load_lds(
                (__attribute__((address_space(1))) void*)gsrc,
                (__attribute__((address_space(3))) void*)((char*)&Bs[cur][0][0] + ((i * 4 + wave) << 10)),
                16, 0, 0);
        }
    };

    auto MF = [&](int cur) {
        const char* Ab = (const char*)&As[cur][0][0];
        const char* Bb = (const char*)&Bs[cur][0][0];
        int r = wave * 16 + c;
        int sw = r & 7;
        f4_t fa0 = *(const f4_t*)(Ab + r * 128 + (((q * 2) ^ sw) << 4));
        f4_t fa1 = *(const f4_t*)(Ab + r * 128 + (((q * 2 + 1) ^ sw) << 4));
        bf8_t af;
        af[0] = (short)f2bf(fa0[0]); af[1] = (short)f2bf(fa0[1]);
        af[2] = (short)f2bf(fa0[2]); af[3] = (short)f2bf(fa0[3]);
        af[4] = (short)f2bf(fa1[0]); af[5] = (short)f2bf(fa1[1]);
        af[6] = (short)f2bf(fa1[2]); af[7] = (short)f2bf(fa1[3]);
#pragma unroll
        for (int nt = 0; nt < 8; ++nt) {
            int rb = nt * 16 + c;
            bf8_t bfr = *(const bf8_t*)(Bb + rb * 64 + ((q ^ ((rb >> 1) & 3)) << 4));
            acc[nt] = __builtin_amdgcn_mfma_f32_16x16x32_bf16(af, bfr, acc[nt], 0, 0, 0);
        }
    };

    STAGE(0, 0);
    int cur = 0;
    for (int k0 = 0; k0 < K; k0 += 32) {
        asm volatile("s_waitcnt vmcnt(0)" ::: "memory");
        __syncthreads();              // buf[cur] staged by all waves; prior reads done
        if (k0 + 32 < K) STAGE(cur ^ 1, k0 + 32);   // in flight through MF below
        MF(cur);
        cur ^= 1;
    }

    float bcol[8], gcol[8], becol[8];
#pragma unroll
    for (int nt = 0; nt < 8; ++nt) {
        bcol[nt] = g.bias[nt * 16 + c];
        if constexpr (EPI == 3) {
            gcol[nt] = g.gamma[nt * 16 + c];
            becol[nt] = g.beta[nt * 16 + c];
        }
    }

#pragma unroll
    for (int r = 0; r < 4; ++r) {
        int grow = row0 + wave * 16 + q * 4 + r;
        float v[8];
#pragma unroll
        for (int nt = 0; nt < 8; ++nt) v[nt] = acc[nt][r] + bcol[nt];
        if constexpr (EPI == 3) {
            float s = 0.f, ss = 0.f;
#pragma unroll
            for (int nt = 0; nt < 8; ++nt) { s += v[nt]; ss += v[nt] * v[nt]; }
#pragma unroll
            for (int m = 8; m >= 1; m >>= 1) {
                s += __shfl_xor(s, m, 64);
                ss += __shfl_xor(ss, m, 64);
            }
            float mu = s * (1.f / 128.f);
            float var = ss * (1.f / 128.f) - mu * mu;
            float rs = rsqrtf(var + 1e-5f);
#pragma unroll
            for (int nt = 0; nt < 8; ++nt)
                v[nt] = fmaxf((v[nt] - mu) * rs * gcol[nt] + becol[nt], 0.f);
        }
        if (g.aMode > 0) {
            float pa[8];
#pragma unroll
            for (int i = 0; i < 8; ++i) pa[i] = 0.f;
#pragma unroll
            for (int nt = 0; nt < 8; ++nt) {
                int col = nt * 16 + c;
                float2 w0 = *(const float2*)&g.wav0[col * 2];
                pa[0] += v[nt] * w0.x; pa[1] += v[nt] * w0.y;
                if (g.aMode > 1) {
                    float2 w1 = *(const float2*)&g.wav1[col * 2];
                    pa[2] += v[nt] * w1.x; pa[3] += v[nt] * w1.y;
                }
                if (g.aMode > 2) {
                    float2 w2 = *(const float2*)&g.wav2[col * 2];
                    float2 w3 = *(const float2*)&g.wav3[col * 2];
                    pa[4] += v[nt] * w2.x; pa[5] += v[nt] * w2.y;
                    pa[6] += v[nt] * w3.x; pa[7] += v[nt] * w3.y;
                }
            }
#pragma unroll
            for (int m = 8; m >= 1; m >>= 1) {
                pa[0] += __shfl_xor(pa[0], m, 64); pa[1] += __shfl_xor(pa[1], m, 64);
                pa[2] += __shfl_xor(pa[2], m, 64); pa[3] += __shfl_xor(pa[3], m, 64);
                pa[4] += __shfl_xor(pa[4], m, 64); pa[5] += __shfl_xor(pa[5], m, 64);
                pa[6] += __shfl_xor(pa[6], m, 64); pa[7] += __shfl_xor(pa[7], m, 64);
            }
            if (c == 0 && grow < g.M) {
                float* ao = &g.aOut[(size_t)grow * g.aStride];
                ao[0] = pa[0]; ao[1] = pa[1];
                if (g.aMode > 1) { ao[2] = pa[2]; ao[3] = pa[3]; }
                if (g.aMode > 2) { ao[4] = pa[4]; ao[5] = pa[5]; ao[6] = pa[6]; ao[7] = pa[7]; }
            }
        }
        if (grow < g.M) {
            unsigned short* Y = (unsigned short*)g.Y;
#pragma unroll
            for (int nt = 0; nt < 8; ++nt)
                Y[(size_t)grow * g.ldY + nt * 16 + c] = f2bf(v[nt]);
        }
    }
}

// ---------------------------------------------------------------------------
// D2a: coalesced interleaved scan (1 block). Thread t owns bins {t, t+256,...}
// (COALESCED loads/stores across the wave). Bin segments are laid out in this
// permuted order — valid because the gather uses [beg, beg+cnt), never
// offs[bin+1].
// ---------------------------------------------------------------------------
__global__ __launch_bounds__(256) void k_scan(
    const int* __restrict__ bcnt, int* __restrict__ offs, int* __restrict__ cur) {
    __shared__ int sums[256];
    int t = threadIdx.x;
    int s = 0;
    for (int i = t; i < NBINS; i += 256) s += bcnt[i];
    sums[t] = s;
    __syncthreads();
    for (int off = 1; off < 256; off <<= 1) {
        int tmp = (t >= off) ? sums[t - off] : 0;
        __syncthreads();
        sums[t] += tmp;
        __syncthreads();
    }
    int run = sums[t] - s;   // exclusive prefix of this thread's chain
    for (int i = t; i < NBINS; i += 256) {
        int v = bcnt[i];
        offs[i] = run;
        cur[i] = run;
        run += v;
    }
}

// ---------------------------------------------------------------------------
// D2b: lin0 GEMM (async-staged) blocks + direct-scatter blocks in one grid.
// Scatter: single pass, pos = atomicAdd(cur[bin]) -> esrc[pos] = src.
// ---------------------------------------------------------------------------
__global__ __launch_bounds__(256) void k_lin0_scat(
    GPair P, int gemmBlocks,
    const int* __restrict__ js_src, const int* __restrict__ js_dst,
    const int* __restrict__ sj_src, const int* __restrict__ sj_dst,
    const int* __restrict__ ss_src, const int* __restrict__ ss_dst,
    int* __restrict__ cur, int* __restrict__ esrc) {
    if (blockIdx.x < (unsigned)gemmBlocks) {
        mgemm_body<3>(P, blockIdx.x);
        return;
    }
    int t = threadIdx.x;
    int sb = blockIdx.x - gemmBlocks;
    const int CH = (ETOT + SCAT_NB - 1) / SCAT_NB;
    const int beg = sb * CH;
    const int endi = (beg + CH < ETOT) ? beg + CH : ETOT;
    if (beg >= ETOT) return;
    for (int e = beg + t; e < endi; e += 256) {
        int src, bin;
        edge_decode(e, js_src, js_dst, sj_src, sj_dst, ss_src, ss_dst, src, bin);
        int pos = atomicAdd(&cur[bin], 1);
        esrc[pos] = src;
    }
}

// ---------------------------------------------------------------------------
// Gather v5: deferred projection. Aggregates 128-dim SOURCE features.
// Quarter-wave (16 lanes) per edge, lane = 8 cols (uint4), both heads from one
// row read. Reduce via shfl_xor {16,32}. End of segment = beg + bcnt[bin].
// ---------------------------------------------------------------------------
__device__ inline void fm8(float p0, float p1, uint4 u, float a0[8], float a1[8]) {
    float x0 = __uint_as_float(u.x << 16);
    float x1 = __uint_as_float(u.x & 0xffff0000u);
    float x2 = __uint_as_float(u.y << 16);
    float x3 = __uint_as_float(u.y & 0xffff0000u);
    float x4 = __uint_as_float(u.z << 16);
    float x5 = __uint_as_float(u.z & 0xffff0000u);
    float x6 = __uint_as_float(u.w << 16);
    float x7 = __uint_as_float(u.w & 0xffff0000u);
    a0[0] += p0 * x0; a0[1] += p0 * x1; a0[2] += p0 * x2; a0[3] += p0 * x3;
    a0[4] += p0 * x4; a0[5] += p0 * x5; a0[6] += p0 * x6; a0[7] += p0 * x7;
    a1[0] += p1 * x0; a1[1] += p1 * x1; a1[2] += p1 * x2; a1[3] += p1 * x3;
    a1[4] += p1 * x4; a1[5] += p1 * x5; a1[6] += p1 * x6; a1[7] += p1 * x7;
}

__device__ inline void rel_run(
    const int* __restrict__ esrc, int beg, int end,
    const float* __restrict__ aSrc, int aShift, int aOff, float adx, float ady,
    const unsigned short* __restrict__ rows, int colOff, int g,
    float a0[8], float a1[8], float& den0, float& den1) {
    int j = beg;
    for (; j + 8 <= end; j += 8) {
        int s0 = esrc[j + g];
        int s1 = esrc[j + 4 + g];
        uint4 u0 = *(const uint4*)&rows[(unsigned)s0 * 128 + colOff];
        uint4 u1 = *(const uint4*)&rows[(unsigned)s1 * 128 + colOff];
        float2 f0 = *(const float2*)&aSrc[((unsigned)s0 << aShift) + aOff];
        float2 f1 = *(const float2*)&aSrc[((unsigned)s1 << aShift) + aOff];
        float e00 = f0.x + adx; e00 = e00 > 0.f ? e00 : 0.2f * e00;
        float e01 = f0.y + ady; e01 = e01 > 0.f ? e01 : 0.2f * e01;
        float e10 = f1.x + adx; e10 = e10 > 0.f ? e10 : 0.2f * e10;
        float e11 = f1.y + ady; e11 = e11 > 0.f ? e11 : 0.2f * e11;
        float p00 = __expf(e00), p01 = __expf(e01);
        float p10 = __expf(e10), p11 = __expf(e11);
        fm8(p00, p01, u0, a0, a1);
        fm8(p10, p11, u1, a0, a1);
        den0 += p00 + p10; den1 += p01 + p11;
    }
    for (; j < end; j += 4) {
        int e = j + g;
        bool ok = e < end;
        int s = esrc[ok ? e : j];
        uint4 u = *(const uint4*)&rows[(unsigned)s * 128 + colOff];
        float2 f = *(const float2*)&aSrc[((unsigned)s << aShift) + aOff];
        float e0 = f.x + adx; e0 = e0 > 0.f ? e0 : 0.2f * e0;
        float e1 = f.y + ady; e1 = e1 > 0.f ? e1 : 0.2f * e1;
        float p0 = ok ? __expf(e0) : 0.f;
        float p1 = ok ? __expf(e1) : 0.f;
        fm8(p0, p1, u, a0, a1);
        den0 += p0; den1 += p1;
    }
}

__device__ inline void store8(unsigned short* dst, const float v[8]) {
    uint4 o;
    o.x = (unsigned)f2bf(v[0]) | ((unsigned)f2bf(v[1]) << 16);
    o.y = (unsigned)f2bf(v[2]) | ((unsigned)f2bf(v[3]) << 16);
    o.z = (unsigned)f2bf(v[4]) | ((unsigned)f2bf(v[5]) << 16);
    o.w = (unsigned)f2bf(v[6]) | ((unsigned)f2bf(v[7]) << 16);
    *(uint4*)dst = o;
}

__device__ inline void finish_store(float a0[8], float a1[8], float den0, float den1,
                                    int lane, unsigned short* base) {
    float d0 = den0; d0 += __shfl_xor(d0, 16, 64); d0 += __shfl_xor(d0, 32, 64);
    float d1 = den1; d1 += __shfl_xor(d1, 16, 64); d1 += __shfl_xor(d1, 32, 64);
    float s0 = 1.f / (d0 + 1e-16f), s1 = 1.f / (d1 + 1e-16f);
    float o0[8], o1[8];
#pragma unroll
    for (int i = 0; i < 8; ++i) {
        float t0 = a0[i]; t0 += __shfl_xor(t0, 16, 64); t0 += __shfl_xor(t0, 32, 64);
        float t1 = a1[i]; t1 += __shfl_xor(t1, 16, 64); t1 += __shfl_xor(t1, 32, 64);
        o0[i] = t0 * s0; o1[i] = t1 * s1;
    }
    if ((lane >> 4) == 0) {
        store8(base, o0);
        store8(base + 128, o1);
    }
}

__global__ __launch_bounds__(256) void k_gather_all(
    const int* __restrict__ offs, const int* __restrict__ bcnt,
    const int* __restrict__ esrc,
    const float* __restrict__ aJ, const float* __restrict__ aS,
    const unsigned short* __restrict__ rowsJ,   // job src rows (ld 128)
    const unsigned short* __restrict__ rowsS,   // skill src rows (ld 128)
    unsigned short* __restrict__ aggS,          // [NS][512]: jsH0|jsH1|ssH0|ssH1
    unsigned short* __restrict__ aggJ,          // [NJ][256]: sjH0|sjH1
    int jobOnly) {
    int wave = threadIdx.x >> 6, lane = threadIdx.x & 63;
    int idx = blockIdx.x * 4 + wave;
    int g = lane >> 4, cl = lane & 15;
    int colOff = cl * 8;

    float a0[8], a1[8], den0, den1;

    if (jobOnly) {
        if (idx >= NJ) return;
        int d = idx;
#pragma unroll
        for (int i = 0; i < 8; ++i) { a0[i] = 0.f; a1[i] = 0.f; }
        den0 = den1 = 0.f;
        int bb = NS + d;
        int beg = offs[bb], end = beg + bcnt[bb];
        float2 ad = *(const float2*)&aJ[(unsigned)d * 4 + 2];
        rel_run(esrc, beg, end, aS, 3, 4, ad.x, ad.y, rowsS, colOff, g, a0, a1, den0, den1);
        finish_store(a0, a1, den0, den1, lane, &aggJ[(size_t)d * 256 + colOff]);
        return;
    }
    if (idx < NS) {
        int d = idx;
#pragma unroll
        for (int i = 0; i < 8; ++i) { a0[i] = 0.f; a1[i] = 0.f; }
        den0 = den1 = 0.f;
        int beg = offs[d], end = beg + bcnt[d];
        float2 adA = *(const float2*)&aS[(unsigned)d * 8 + 2];
        rel_run(esrc, beg, end, aJ, 2, 0, adA.x, adA.y, rowsJ, colOff, g, a0, a1, den0, den1);
        finish_store(a0, a1, den0, den1, lane, &aggS[(size_t)d * 512 + colOff]);
#pragma unroll
        for (int i = 0; i < 8; ++i) { a0[i] = 0.f; a1[i] = 0.f; }
        den0 = den1 = 0.f;
        int bb = NS + NJ + d;
        int beg2 = offs[bb], end2 = beg2 + bcnt[bb];
        float2 adB = *(const float2*)&aS[(unsigned)d * 8 + 6];
        rel_run(esrc, beg2, end2, aS, 3, 0, adB.x, adB.y, rowsS, colOff, g, a0, a1, den0, den1);
        finish_store(a0, a1, den0, den1, lane, &aggS[(size_t)d * 512 + 256 + colOff]);
    } else if (idx < NS + NJ) {
        int d = idx - NS;
#pragma unroll
        for (int i = 0; i < 8; ++i) { a0[i] = 0.f; a1[i] = 0.f; }
        den0 = den1 = 0.f;
        int bb = NS + d;
        int beg = offs[bb], end = beg + bcnt[bb];
        float2 ad = *(const float2*)&aJ[(unsigned)d * 4 + 2];
        rel_run(esrc, beg, end, aS, 3, 4, ad.x, ad.y, rowsS, colOff, g, a0, a1, den0, den1);
        finish_store(a0, a1, den0, den1, lane, &aggJ[(size_t)d * 256 + colOff]);
    }
}

// ---------------------------------------------------------------------------
// D6: two-stage fused GEMM, single-pass stage1. Both 128-col output halves of
// stage1 are computed in ONE K-pass (Bl holds 256 weight rows; acc0/acc1 in
// registers). Stage2 consumes each half from Y1l[4] in its K-slice.
// LDS = Al(5K)+Bl(20.5K)+Y1l(20.5K) = 46KB -> 3 blocks/CU.
// ---------------------------------------------------------------------------
struct FJob {
    const unsigned short* X; int K1; int M;
    const unsigned short* Wt1; const float* bias1;
    const unsigned short* Wt2; const float* bias2;
    const float* wa; float* aOut; int aStride;
    unsigned short* Y2;                          // nullable; ld 128
};
struct FPair { FJob a; FJob b; int blocksA; };

__global__ __launch_bounds__(256) void k_fused2(FPair P) {
    int mb = blockIdx.x;
    FJob g = (mb < P.blocksA) ? P.a : P.b;
    if (mb >= P.blocksA) mb -= P.blocksA;
    const int row0 = mb * 64;
    const int K1 = g.K1;

    __shared__ __align__(16) unsigned short Al[64][40];
    __shared__ __align__(16) unsigned short Bl[256][40];
    __shared__ __align__(16) unsigned short Y1l[4][64][40];
    const int t = threadIdx.x;
    const int wave = t >> 6, lane = t & 63;
    const int q = lane >> 4, c = lane & 15;

    f4_t acc0[8], acc1[8], acc2[8];
#pragma unroll
    for (int nt = 0; nt < 8; ++nt) {
        acc0[nt] = (f4_t){0.f, 0.f, 0.f, 0.f};
        acc1[nt] = (f4_t){0.f, 0.f, 0.f, 0.f};
        acc2[nt] = (f4_t){0.f, 0.f, 0.f, 0.f};
    }

    // stage1: single K-pass, both column halves
    for (int k0 = 0; k0 < K1; k0 += 32) {
#pragma unroll
        for (int it = 0; it < 5; ++it) {
            int idx = t + it * 256;
            int r = idx >> 2, cc = (idx & 3) * 8;
            if (r < 64) {
                int gr = row0 + r;
                uint4 va = (gr < g.M) ? *(const uint4*)&g.X[(size_t)gr * K1 + k0 + cc]
                                      : make_uint4(0u, 0u, 0u, 0u);
                *(uint4*)&Al[r][cc] = va;
            } else {
                int br = r - 64;   // 0..255
                *(uint4*)&Bl[br][cc] = *(const uint4*)&g.Wt1[(size_t)br * K1 + k0 + cc];
            }
        }
        __syncthreads();
        bf8_t af = *(const bf8_t*)&Al[wave * 16 + c][q * 8];
#pragma unroll
        for (int nt = 0; nt < 8; ++nt) {
            bf8_t b0 = *(const bf8_t*)&Bl[nt * 16 + c][q * 8];
            acc0[nt] = __builtin_amdgcn_mfma_f32_16x16x32_bf16(af, b0, acc0[nt], 0, 0, 0);
            bf8_t b1 = *(const bf8_t*)&Bl[128 + nt * 16 + c][q * 8];
            acc1[nt] = __builtin_amdgcn_mfma_f32_16x16x32_bf16(af, b1, acc1[nt], 0, 0, 0);
        }
        __syncthreads();
    }

    // per half: park in Y1l, run stage2 K-slice
#pragma unroll
    for (int np = 0; np < 2; ++np) {
        float bcol[8];
#pragma unroll
        for (int nt = 0; nt < 8; ++nt) bcol[nt] = g.bias1[np * 128 + nt * 16 + c];
#pragma unroll
        for (int r = 0; r < 4; ++r) {
            int row = wave * 16 + q * 4 + r;
#pragma unroll
            for (int nt = 0; nt < 8; ++nt) {
                float vv = (np ? acc1[nt][r] : acc0[nt][r]) + bcol[nt];
                Y1l[nt >> 1][row][(nt & 1) * 16 + c] = f2bf(vv);
            }
        }
        __syncthreads();
        for (int k0 = 0; k0 < 128; k0 += 32) {
#pragma unroll
            for (int it = 0; it < 2; ++it) {
                int idx = t + it * 256;
                int br = idx >> 2, cc = (idx & 3) * 8;
                *(uint4*)&Bl[br][cc] = *(const uint4*)&g.Wt2[(size_t)br * 256 + np * 128 + k0 + cc];
            }
            __syncthreads();
            bf8_t af = *(const bf8_t*)&Y1l[k0 >> 5][wave * 16 + c][q * 8];
#pragma unroll
            for (int nt = 0; nt < 8; ++nt) {
                bf8_t bfr = *(const bf8_t*)&Bl[nt * 16 + c][q * 8];
                acc2[nt] = __builtin_amdgcn_mfma_f32_16x16x32_bf16(af, bfr, acc2[nt], 0, 0, 0);
            }
            __syncthreads();
        }
    }

    float b2[8];
#pragma unroll
    for (int nt = 0; nt < 8; ++nt) b2[nt] = g.bias2[nt * 16 + c];
#pragma unroll
    for (int r = 0; r < 4; ++r) {
        int grow = row0 + wave * 16 + q * 4 + r;
        float v[8];
#pragma unroll
        for (int nt = 0; nt < 8; ++nt) v[nt] = fmaxf(acc2[nt][r] + b2[nt], 0.f);
        if (g.wa) {
            float pa0 = 0.f, pa1 = 0.f;
#pragma unroll
            for (int nt = 0; nt < 8; ++nt) {
                float2 w0 = *(const float2*)&g.wa[(nt * 16 + c) * 2];
                pa0 += v[nt] * w0.x; pa1 += v[nt] * w0.y;
            }
#pragma unroll
            for (int m = 8; m >= 1; m >>= 1) {
                pa0 += __shfl_xor(pa0, m, 64);
                pa1 += __shfl_xor(pa1, m, 64);
            }
            if (c == 0 && grow < g.M) {
                g.aOut[(size_t)grow * g.aStride + 0] = pa0;
                g.aOut[(size_t)grow * g.aStride + 1] = pa1;
            }
        }
        if (g.Y2 && grow < g.M) {
#pragma unroll
            for (int nt = 0; nt < 8; ++nt)
                g.Y2[(size_t)grow * 128 + nt * 16 + c] = f2bf(v[nt]);
        }
    }
}

// ---------------------------------------------------------------------------
// D8: three-stage fused GEMM, single-pass stage1 (same restructure as
// k_fused2); Yl reused for stage2 output (stage3 input). 46KB LDS.
// ---------------------------------------------------------------------------
struct F3 {
    const unsigned short* X; int M;
    const unsigned short* Wt1; const float* bias1;
    const unsigned short* Wt2; const float* bias2;
    const unsigned short* Wt3; const float* bias3;
    const float* qv; float* sc; float* Y;
};

__global__ __launch_bounds__(256) void k_fused3(F3 g) {
    int mb = blockIdx.x;
    const int row0 = mb * 64;
    __shared__ __align__(16) unsigned short Al[64][40];
    __shared__ __align__(16) unsigned short Bl[256][40];
    __shared__ __align__(16) unsigned short Yl[4][64][40];
    const int t = threadIdx.x;
    const int wave = t >> 6, lane = t & 63;
    const int q = lane >> 4, c = lane & 15;

    f4_t acc0[8], acc1[8], acc2[8];
#pragma unroll
    for (int nt = 0; nt < 8; ++nt) {
        acc0[nt] = (f4_t){0.f, 0.f, 0.f, 0.f};
        acc1[nt] = (f4_t){0.f, 0.f, 0.f, 0.f};
        acc2[nt] = (f4_t){0.f, 0.f, 0.f, 0.f};
    }

    // stage1: single K-pass over 256, both column halves
    for (int k0 = 0; k0 < 256; k0 += 32) {
#pragma unroll
        for (int it = 0; it < 5; ++it) {
            int idx = t + it * 256;
            int r = idx >> 2, cc = (idx & 3) * 8;
            if (r < 64) {
                int gr = row0 + r;
                uint4 va = (gr < g.M) ? *(const uint4*)&g.X[(size_t)gr * 256 + k0 + cc]
                                      : make_uint4(0u, 0u, 0u, 0u);
                *(uint4*)&Al[r][cc] = va;
            } else {
                int br = r - 64;
                *(uint4*)&Bl[br][cc] = *(const uint4*)&g.Wt1[(size_t)br * 256 + k0 + cc];
            }
        }
        __syncthreads();
        bf8_t af = *(const bf8_t*)&Al[wave * 16 + c][q * 8];
#pragma unroll
        for (int nt = 0; nt < 8; ++nt) {
            bf8_t b0 = *(const bf8_t*)&Bl[nt * 16 + c][q * 8];
            acc0[nt] = __builtin_amdgcn_mfma_f32_16x16x32_bf16(af, b0, acc0[nt], 0, 0, 0);
            bf8_t b1 = *(const bf8_t*)&Bl[128 + nt * 16 + c][q * 8];
            acc1[nt] = __builtin_amdgcn_mfma_f32_16x16x32_bf16(af, b1, acc1[nt], 0, 0, 0);
        }
        __syncthreads();
    }

    // per half: park in Yl, run stage2 K-slice
#pragma unroll
    for (int np = 0; np < 2; ++np) {
        float bcol[8];
#pragma unroll
        for (int nt = 0; nt < 8; ++nt) bcol[nt] = g.bias1[np * 128 + nt * 16 + c];
#pragma unroll
        for (int r = 0; r < 4; ++r) {
            int row = wave * 16 + q * 4 + r;
#pragma unroll
            for (int nt = 0; nt < 8; ++nt) {
                float vv = (np ? acc1[nt][r] : acc0[nt][r]) + bcol[nt];
                Yl[nt >> 1][row][(nt & 1) * 16 + c] = f2bf(vv);
            }
        }
        __syncthreads();
        for (int k0 = 0; k0 < 128; k0 += 32) {
#pragma unroll
            for (int it = 0; it < 2; ++it) {
                int idx = t + it * 256;
                int br = idx >> 2, cc = (idx & 3) * 8;
                *(uint4*)&Bl[br][cc] = *(const uint4*)&g.Wt2[(size_t)br * 256 + np * 128 + k0 + cc];
            }
            __syncthreads();
            bf8_t af = *(const bf8_t*)&Yl[k0 >> 5][wave * 16 + c][q * 8];
#pragma unroll
            for (int nt = 0; nt < 8; ++nt) {
                bf8_t bfr = *(const bf8_t*)&Bl[nt * 16 + c][q * 8];
                acc2[nt] = __builtin_amdgcn_mfma_f32_16x16x32_bf16(af, bfr, acc2[nt], 0, 0, 0);
            }
            __syncthreads();
        }
    }

    // stage2 epilogue: bias + relu -> Yl (prior contents fully consumed)
    {
        float b2[8];
#pragma unroll
        for (int nt = 0; nt < 8; ++nt) b2[nt] = g.bias2[nt * 16 + c];
#pragma unroll
        for (int r = 0; r < 4; ++r) {
            int row = wave * 16 + q * 4 + r;
#pragma unroll
            for (int nt = 0; nt < 8; ++nt)
                Yl[nt >> 1][row][(nt & 1) * 16 + c] = f2bf(fmaxf(acc2[nt][r] + b2[nt], 0.f));
        }
        __syncthreads();
    }

    // stage3: 128 -> 128, f32 out + scores
    f4_t acc3[8];
#pragma unroll
    for (int nt = 0; nt < 8; ++nt) acc3[nt] = (f4_t){0.f, 0.f, 0.f, 0.f};
    for (int k0 = 0; k0 < 128; k0 += 32) {
#pragma unroll
        for (int it = 0; it < 2; ++it) {
            int idx = t + it * 256;
            int br = idx >> 2, cc = (idx & 3) * 8;
            *(uint4*)&Bl[br][cc] = *(const uint4*)&g.Wt3[(size_t)br * 128 + k0 + cc];
        }
        __syncthreads();
        bf8_t af = *(const bf8_t*)&Yl[k0 >> 5][wave * 16 + c][q * 8];
#pragma unroll
        for (int nt = 0; nt < 8; ++nt) {
            bf8_t bfr = *(const bf8_t*)&Bl[nt * 16 + c][q * 8];
            acc3[nt] = __builtin_amdgcn_mfma_f32_16x16x32_bf16(af, bfr, acc3[nt], 0, 0, 0);
        }
        __syncthreads();
    }
    float b3[8], qcol[8];
#pragma unroll
    for (int nt = 0; nt < 8; ++nt) {
        b3[nt] = g.bias3[nt * 16 + c];
        qcol[nt] = g.qv[nt * 16 + c];
    }
#pragma unroll
    for (int r = 0; r < 4; ++r) {
        int grow = row0 + wave * 16 + q * 4 + r;
        float v[8];
#pragma unroll
        for (int nt = 0; nt < 8; ++nt) v[nt] = acc3[nt][r] + b3[nt];
        float part = 0.f;
#pragma unroll
        for (int nt = 0; nt < 8; ++nt) part += v[nt] * qcol[nt];
#pragma unroll
        for (int m = 8; m >= 1; m >>= 1) part += __shfl_xor(part, m, 64);
        if (grow < g.M) {
            if (c == 0) g.sc[grow] = part;
#pragma unroll
            for (int nt = 0; nt < 8; ++nt)
                g.Y[(size_t)grow * 128 + nt * 16 + c] = v[nt];
        }
    }
}

// ---------------------------------------------------------------------------
extern "C" void kernel_launch(void* const* d_in, const int* in_sizes, int n_in,
                              void* d_out, int out_size, void* d_ws, size_t ws_size,
                              hipStream_t stream) {
    const float* x_job   = (const float*)d_in[0];
    const float* x_skill = (const float*)d_in[1];
    const int* js_src = (const int*)d_in[2];
    const int* js_dst = (const int*)d_in[3];
    const int* sj_src = (const int*)d_in[4];
    const int* sj_dst = (const int*)d_in[5];
    const int* ss_src = (const int*)d_in[6];
    const int* ss_dst = (const int*)d_in[7];
    const float* query    = (const float*)d_in[8];
    const float* W0_job   = (const float*)d_in[9];
    const float* b0_job   = (const float*)d_in[10];
    const float* g0_job   = (const float*)d_in[11];
    const float* be0_job  = (const float*)d_in[12];
    const float* W0_skill = (const float*)d_in[13];
    const float* b0_skill = (const float*)d_in[14];
    const float* g0_skill = (const float*)d_in[15];
    const float* be0_skill= (const float*)d_in[16];
    const float* gat_Ws = (const float*)d_in[17];
    const float* gat_Wd = (const float*)d_in[18];
    const float* gat_as = (const float*)d_in[19];
    const float* gat_ad = (const float*)d_in[20];
    const float* gat_b  = (const float*)d_in[21];
    const float* inter_W = (const float*)d_in[22];
    const float* inter_b = (const float*)d_in[23];
    const float* Wjf = (const float*)d_in[24];
    const float* bjf = (const float*)d_in[25];
    const float* Wq  = (const float*)d_in[26];
    const float* bq  = (const float*)d_in[27];

    char* w = (char*)d_ws;
    auto alloc = [&](size_t bytes) -> void* {
        void* p = (void*)w;
        w += (bytes + 255) & ~(size_t)255;
        return p;
    };
    u16* xj   = (u16*)alloc((size_t)NJ * 128 * 2);
    u16* xs   = (u16*)alloc((size_t)NS * 128 * 2);
    u16* xs1  = (u16*)alloc((size_t)NS * 128 * 2);
    u16* aggJ  = (u16*)alloc((size_t)NJ * 256 * 2);
    u16* aggJ1 = (u16*)alloc((size_t)NJ * 256 * 2);
    u16* aggS  = (u16*)alloc((size_t)NS * 512 * 2);
    u16* WtW0j = (u16*)alloc((size_t)SBERT * 128 * 2);
    u16* WtW0s = (u16*)alloc((size_t)SBERT * 128 * 2);
    u16* WsS1  = (u16*)alloc((size_t)256 * 512 * 2);
    u16* WsJ0  = (u16*)alloc((size_t)256 * 256 * 2);
    u16* WsJ1  = (u16*)alloc((size_t)256 * 256 * 2);
    u16* WtI00 = (u16*)alloc((size_t)128 * 256 * 2);
    u16* WtI01 = (u16*)alloc((size_t)128 * 256 * 2);
    u16* WtI10 = (u16*)alloc((size_t)128 * 256 * 2);
    u16* WtJf  = (u16*)alloc((size_t)128 * 128 * 2);
    float* gbS = (float*)alloc(256 * 4);
    float* aJ = (float*)alloc((size_t)NJ * 4 * 4);
    float* aS = (float*)alloc((size_t)NS * 8 * 4);
    float* wsa = (float*)alloc(6 * 256 * 4);
    float* wda = (float*)alloc(6 * 256 * 4);
    int* bcnt = (int*)alloc((size_t)NBINS * 4);
    int* offs = (int*)alloc((size_t)NBINS * 4);
    int* curb = (int*)alloc((size_t)NBINS * 4);
    int* esrc = (int*)alloc((size_t)ETOT * 4);

    float* out = (float*)d_out;
    float* scores  = out;
    float* job_emb = out + NJ;
    float* qv      = out + NJ + (size_t)NJ * 128;

    const int mbJ = cdiv(NJ, 64);   // 469
    const int mbS = cdiv(NS, 64);   // 188
    const int gemmB = mbJ + mbS;    // 657

    // M0: zero bin counters + structured weight buffers (block layouts)
    hipMemsetAsync(bcnt, 0, (size_t)NBINS * 4, stream);
    hipMemsetAsync(WsS1, 0, (size_t)256 * 512 * 2, stream);
    hipMemsetAsync(WsJ0, 0, (size_t)256 * 256 * 2, stream);
    hipMemsetAsync(WsJ1, 0, (size_t)256 * 256 * 2, stream);

    // D1: prep (weight casts/structured layouts + wa + qvec + gbS + hist)
    {
        const size_t WS = (size_t)128 * 256;
        const size_t IW = (size_t)256 * 128;
        PrepArgs A;
        A.m[0]  = {W0_job,   WtW0j, SBERT, 128, 128, SBERT};
        A.m[1]  = {W0_skill, WtW0s, SBERT, 128, 128, SBERT};
        // WsS1 (256x512): [n<128,k<128]=Ws00[:,:128]; [n>=128,k 128..256)=Ws00[:,128:]
        //                 [n<128,k 256..384)=Ws02[:,:128]; [n>=128,k 384..512)=Ws02[:,128:]
        A.m[2]  = {gat_Ws + 0 * WS,       WsS1,                       128, 128, 256, 512};
        A.m[3]  = {gat_Ws + 0 * WS + 128, WsS1 + 128 * 512 + 128,     128, 128, 256, 512};
        A.m[4]  = {gat_Ws + 2 * WS,       WsS1 + 256,                 128, 128, 256, 512};
        A.m[5]  = {gat_Ws + 2 * WS + 128, WsS1 + 128 * 512 + 384,     128, 128, 256, 512};
        // WsJ0 (256x256): block-diag from Ws01
        A.m[6]  = {gat_Ws + 1 * WS,       WsJ0,                       128, 128, 256, 256};
        A.m[7]  = {gat_Ws + 1 * WS + 128, WsJ0 + 128 * 256 + 128,     128, 128, 256, 256};
        // WsJ1 (256x256): block-diag from Ws11
        A.m[8]  = {gat_Ws + 4 * WS,       WsJ1,                       128, 128, 256, 256};
        A.m[9]  = {gat_Ws + 4 * WS + 128, WsJ1 + 128 * 256 + 128,     128, 128, 256, 256};
        A.m[10] = {inter_W + 0 * IW, WtI00, 256, 128, 128, 256};
        A.m[11] = {inter_W + 1 * IW, WtI01, 256, 128, 128, 256};
        A.m[12] = {inter_W + 2 * IW, WtI10, 256, 128, 128, 256};
        A.m[13] = {Wjf, WtJf, 128, 128, 128, 128};
        A.Ws = gat_Ws; A.as_ = gat_as; A.Wd = gat_Wd; A.ad_ = gat_ad;
        A.wsa = wsa; A.wda = wda; A.bcnt = bcnt;
        A.query = query; A.Wq = Wq; A.bq = bq; A.qv = qv;
        A.gat_b = gat_b; A.gbS = gbS;
        A.js_src = js_src; A.js_dst = js_dst;
        A.sj_src = sj_src; A.sj_dst = sj_dst;
        A.ss_src = ss_src; A.ss_dst = ss_dst;
        k_prep<<<PREP_HIST + HIST_NB, 256, 0, stream>>>(A);
    }

    // D2a: coalesced interleaved bin scan (1 block)
    k_scan<<<1, 256, 0, stream>>>(bcnt, offs, curb);

    // D2b: lin0 GEMM + direct-scatter blocks merged
    {
        GPair P;
        P.a = {x_job, WtW0j, b0_job, g0_job, be0_job, xj, NJ, SBERT, 128, 128, 1,
               nullptr, nullptr, 2, wsa + 0, wda + 256, nullptr, nullptr, aJ, 4};
        P.b = {x_skill, WtW0s, b0_skill, g0_skill, be0_skill, xs, NS, SBERT, 128, 128, 1,
               nullptr, nullptr, 4, wsa + 2 * 256, wda + 0, wsa + 1 * 256, wda + 2 * 256, aS, 8};
        P.blocksA = mbJ;
        k_lin0_scat<<<gemmB + SCAT_NB, 256, 0, stream>>>(
            P, gemmB, js_src, js_dst, sj_src, sj_dst, ss_src, ss_dst, curb, esrc);
    }

    // D5: gather l0 — aggregate 128-dim source features (both heads)
    k_gather_all<<<cdiv(NS + NJ, 4), 256, 0, stream>>>(
        offs, bcnt, esrc, aJ, aS, xj, xs, aggS, aggJ, 0);

    // D6: fused Ws-proj + inter (relu) + alpha-l1. Job: no Y2 store needed.
    {
        FPair P;
        P.a = {aggJ, 256, NJ, WsJ0, gat_b + 256, WtI00, inter_b + 0,
               wda + 4 * 256, aJ + 2, 4, nullptr};
        P.b = {aggS, 512, NS, WsS1, gbS, WtI01, inter_b + 128,
               wsa + 4 * 256, aS + 4, 8, xs1};
        P.blocksA = mbJ;
        k_fused2<<<gemmB, 256, 0, stream>>>(P);
    }

    // D7: gather l1 (job dsts only; srcs are xs1, 3MB working set)
    k_gather_all<<<cdiv(NJ, 4), 256, 0, stream>>>(
        offs, bcnt, esrc, aJ, aS, nullptr, xs1, nullptr, aggJ1, 1);

    // D8: fused Ws-proj + inter(relu) + final projection + scores
    {
        F3 g3;
        g3.X = aggJ1; g3.M = NJ;
        g3.Wt1 = WsJ1; g3.bias1 = gat_b + 4 * 256;
        g3.Wt2 = WtI10; g3.bias2 = inter_b + 2 * 128;
        g3.Wt3 = WtJf; g3.bias3 = bjf;
        g3.qv = qv; g3.sc = scores; g3.Y = job_emb;
        k_fused3<<<mbJ, 256, 0, stream>>>(g3);
    }
}

// Round 13
// 346.229 us; speedup vs baseline: 1.4140x; 1.1977x over previous
//
#include <hip/hip_runtime.h>
#include <hip/hip_bf16.h>
#include <math.h>

#define NJ 30000
#define NS 12000
#define E_JS 300000
#define E_SJ 300000
#define E_SS 150000
#define ETOT (E_JS + E_SJ + E_SS + NS)   // 762000 incl. ss self loops
#define NBINS (NS + NJ + NS)             // 54000 combined dst bins
#define NBUK ((NBINS + 63) / 64)         // 844 coarse buckets
#define SBERT 384
#define HIST_NB 512
#define SCAT_NB 480
#define CAST_MATS 14
#define CAST_BPM 48
#define PREP_CAST (CAST_MATS * CAST_BPM)          // 672
#define PREP_WA   (PREP_CAST + 192)               // 864 (quarter-wave per output)
#define PREP_QV   PREP_WA                         // 864
#define PREP_GB   (PREP_QV + 1)                   // 865
#define PREP_HIST (PREP_GB + 1)                   // 866

static inline int cdiv(int a, int b) { return (a + b - 1) / b; }

typedef __attribute__((ext_vector_type(8))) short bf8_t;
typedef __attribute__((ext_vector_type(4))) float f4_t;
typedef unsigned short u16;

__device__ inline float bf2f(unsigned short u) {
    union { unsigned int i; float f; } z; z.i = ((unsigned int)u) << 16; return z.f;
}
__device__ inline unsigned short f2bf(float f) {
    unsigned int x = __float_as_uint(f);
    unsigned int r = (x + 0x7fffu + ((x >> 16) & 1u)) >> 16;   // RNE
    return (unsigned short)r;
}

// ---------------------------------------------------------------------------
// edge decode; bin layout: [0,NS) js | [NS,NS+NJ) sj | [NS+NJ,NBINS) ss+loops
// ---------------------------------------------------------------------------
__device__ inline void edge_decode(int e, const int* js_src, const int* js_dst,
                                   const int* sj_src, const int* sj_dst,
                                   const int* ss_src, const int* ss_dst,
                                   int& src, int& bin) {
    if (e < E_JS) { src = js_src[e]; bin = js_dst[e]; }
    else if (e < E_JS + E_SJ) { int i = e - E_JS; src = sj_src[i]; bin = NS + sj_dst[i]; }
    else if (e < E_JS + E_SJ + E_SS) { int i = e - E_JS - E_SJ; src = ss_src[i]; bin = NS + NJ + ss_dst[i]; }
    else { int i = e - E_JS - E_SJ - E_SS; src = i; bin = NS + NJ + i; }
}

// ---------------------------------------------------------------------------
// D1 k_prep: castT [0,672) | wa [672,864) | qvec [864] | gbS [865] | hist...
// bcnt / WsS1 / WsJ0 / WsJ1 zeroed by hipMemsetAsync before this dispatch.
// Generalized transposed cast: dst[n*dstLd + k] = bf16(src[k*srcLd + n]).
// wa: quarter-wave (16 lanes) per output — coalesced float4 dot + shfl reduce.
// ---------------------------------------------------------------------------
struct CastT { const float* src; unsigned short* dst; int K; int N; int srcLd; int dstLd; };
struct PrepArgs {
    CastT m[CAST_MATS];
    const float* Ws; const float* as_; const float* Wd; const float* ad_;
    float* wsa; float* wda; int* bcnt;
    const float* query; const float* Wq; const float* bq; float* qv;
    const float* gat_b; float* gbS;
    const int* js_src; const int* js_dst;
    const int* sj_src; const int* sj_dst;
    const int* ss_src; const int* ss_dst;
};

__global__ __launch_bounds__(256) void k_prep(PrepArgs A) {
    __shared__ float ldt[32][33];
    __shared__ int lh[NBUK];
    int b = blockIdx.x;
    if (b < PREP_CAST) {
        int mi = b / CAST_BPM, bx = b % CAST_BPM;
        CastT cm = A.m[mi];
        int tilesN = cm.N >> 5;
        int total = (cm.K >> 5) * tilesN;
        if (bx >= total) return;
        int tk = bx / tilesN, tn = bx % tilesN;
        int k0 = tk * 32, n0 = tn * 32;
        int col = threadIdx.x & 31;
        int row0 = threadIdx.x >> 5;
#pragma unroll
        for (int r = 0; r < 4; ++r) {
            int kk = row0 + r * 8;
            ldt[kk][col] = cm.src[(size_t)(k0 + kk) * cm.srcLd + n0 + col];
        }
        __syncthreads();
#pragma unroll
        for (int r = 0; r < 4; ++r) {
            int nn = row0 + r * 8;
            cm.dst[(size_t)(n0 + nn) * cm.dstLd + k0 + col] = f2bf(ldt[col][nn]);
        }
    } else if (b < PREP_WA) {
        int qw = ((b - PREP_CAST) * 256 + threadIdx.x) >> 4;   // quarter-wave id
        int cl = threadIdx.x & 15;
        if (qw < 2 * 1536) {
            int which = qw / 1536;
            int r = qw % 1536;
            int lr = r / 256;
            int kh = r % 256;
            int k = kh / 2, h = kh % 2;
            const float* W = which ? A.Wd : A.Ws;
            const float* a = which ? A.ad_ : A.as_;
            const float* wrow = W + ((size_t)(lr * 128 + k)) * 256 + h * 128 + cl * 8;
            const float* arow = a + (size_t)(lr * 2 + h) * 128 + cl * 8;
            float4 w0 = *(const float4*)wrow, w1 = *(const float4*)(wrow + 4);
            float4 a0 = *(const float4*)arow, a1 = *(const float4*)(arow + 4);
            float acc = w0.x * a0.x + w0.y * a0.y + w0.z * a0.z + w0.w * a0.w
                      + w1.x * a1.x + w1.y * a1.y + w1.z * a1.z + w1.w * a1.w;
            acc += __shfl_xor(acc, 1, 64);
            acc += __shfl_xor(acc, 2, 64);
            acc += __shfl_xor(acc, 4, 64);
            acc += __shfl_xor(acc, 8, 64);
            if (cl == 0) (which ? A.wda : A.wsa)[lr * 256 + k * 2 + h] = acc;
        }
    } else if (b == PREP_QV) {
        int c = threadIdx.x;
        if (c < 128) {
            float acc = A.bq[c];
            for (int k = 0; k < SBERT; ++k) acc += A.query[k] * A.Wq[(size_t)k * 128 + c];
            A.qv[c] = acc;
        }
    } else if (b == PREP_GB) {
        int c = threadIdx.x;
        if (c < 256) A.gbS[c] = A.gat_b[c] + A.gat_b[512 + c];   // gb(0,0)+gb(0,2)
    } else {
        int t = threadIdx.x;
        for (int i = t; i < NBUK; i += 256) lh[i] = 0;
        __syncthreads();
        int hb = b - PREP_HIST;
        for (int e = hb * 256 + t; e < ETOT; e += HIST_NB * 256) {
            int src, bin;
            edge_decode(e, A.js_src, A.js_dst, A.sj_src, A.sj_dst, A.ss_src, A.ss_dst, src, bin);
            atomicAdd(&lh[bin >> 6], 1);
        }
        __syncthreads();
        for (int i = t; i < NBUK; i += 256) {
            int v = lh[i];
            if (v) atomicAdd(&A.bcnt[i], v);
        }
    }
}

// ---------------------------------------------------------------------------
// MFMA GEMM body for D2 lin0 (fp32 X, K=384). BM=64, 4 waves x (16m x 128n).
// Async staging: global_load_lds width-16 into linear LDS, XOR-block-swizzled
// on the GLOBAL source; reads apply the same swizzle. ONE barrier per K-step;
// stage for tile k+1 issued right after the barrier, in flight through MFMA.
//   A: fp32 [64][32], 8x16B blocks/row, swz b^=(row&7); bf16-convert at read.
//   B: bf16 [128][32], 4x16B blocks/row, swz b^=((row>>1)&3).
// EPI 3: +bias,LN,relu->bf16, with alpha epilogue (aMode pairs).
// ---------------------------------------------------------------------------
struct GJob {
    const void* X; const unsigned short* Wt;
    const float* bias; const float* gamma; const float* beta;
    void* Y; int M; int K; int N; int ldY; int srcf32;
    const float* qv; float* sc;
    int aMode = 0;
    const float* wav0 = nullptr; const float* wav1 = nullptr;
    const float* wav2 = nullptr; const float* wav3 = nullptr;
    float* aOut = nullptr; int aStride = 0;
};
struct GPair { GJob a; GJob b; int blocksA; };

template <int EPI>
__device__ void mgemm_body(const GPair& P, int bx) {
    int mb = bx;
    GJob g = (mb < P.blocksA) ? P.a : P.b;
    if (mb >= P.blocksA) mb -= P.blocksA;
    const int row0 = mb * 64;

    __shared__ __align__(16) float As[2][64][32];           // 16 KB
    __shared__ __align__(16) unsigned short Bs[2][128][32]; // 16 KB
    const int t = threadIdx.x;
    const int wave = t >> 6, lane = t & 63;
    const int q = lane >> 4, c = lane & 15;
    const int K = g.K;
    const float* Xf = (const float*)g.X;

    f4_t acc[8];
#pragma unroll
    for (int nt = 0; nt < 8; ++nt) acc[nt] = (f4_t){0.f, 0.f, 0.f, 0.f};

    auto STAGE = [&](int cur, int k0) {
#pragma unroll
        for (int i = 0; i < 2; ++i) {
            int bi = i * 256 + t;
            int row = bi >> 3, b = bi & 7;
            int ra = row0 + row; ra = (ra < g.M) ? ra : (g.M - 1);
            const float* gsrc = Xf + (size_t)ra * K + k0 + ((b ^ (row & 7)) << 2);
            __builtin_amdgcn_global_load_lds(
                (__attribute__((address_space(1))) void*)gsrc,
                (__attribute__((address_space(3))) void*)((char*)&As[cur][0][0] + ((i * 4 + wave) << 10)),
                16, 0, 0);
        }
#pragma unroll
        for (int i = 0; i < 2; ++i) {
            int bi = i * 256 + t;
            int row = bi >> 2, b = bi & 3;
            const unsigned short* gsrc = g.Wt + (size_t)row * K + k0 + ((b ^ ((row >> 1) & 3)) << 3);
            __builtin_amdgcn_global_load_lds(
                (__attribute__((address_space(1))) void*)gsrc,
                (__attribute__((address_space(3))) void*)((char*)&Bs[cur][0][0] + ((i * 4 + wave) << 10)),
                16, 0, 0);
        }
    };

    auto MF = [&](int cur) {
        const char* Ab = (const char*)&As[cur][0][0];
        const char* Bb = (const char*)&Bs[cur][0][0];
        int r = wave * 16 + c;
        int sw = r & 7;
        f4_t fa0 = *(const f4_t*)(Ab + r * 128 + (((q * 2) ^ sw) << 4));
        f4_t fa1 = *(const f4_t*)(Ab + r * 128 + (((q * 2 + 1) ^ sw) << 4));
        bf8_t af;
        af[0] = (short)f2bf(fa0[0]); af[1] = (short)f2bf(fa0[1]);
        af[2] = (short)f2bf(fa0[2]); af[3] = (short)f2bf(fa0[3]);
        af[4] = (short)f2bf(fa1[0]); af[5] = (short)f2bf(fa1[1]);
        af[6] = (short)f2bf(fa1[2]); af[7] = (short)f2bf(fa1[3]);
#pragma unroll
        for (int nt = 0; nt < 8; ++nt) {
            int rb = nt * 16 + c;
            bf8_t bfr = *(const bf8_t*)(Bb + rb * 64 + ((q ^ ((rb >> 1) & 3)) << 4));
            acc[nt] = __builtin_amdgcn_mfma_f32_16x16x32_bf16(af, bfr, acc[nt], 0, 0, 0);
        }
    };

    STAGE(0, 0);
    int cur = 0;
    for (int k0 = 0; k0 < K; k0 += 32) {
        asm volatile("s_waitcnt vmcnt(0)" ::: "memory");
        __syncthreads();              // buf[cur] staged by all waves; prior reads done
        if (k0 + 32 < K) STAGE(cur ^ 1, k0 + 32);   // in flight through MF below
        MF(cur);
        cur ^= 1;
    }

    float bcol[8], gcol[8], becol[8];
#pragma unroll
    for (int nt = 0; nt < 8; ++nt) {
        bcol[nt] = g.bias[nt * 16 + c];
        if constexpr (EPI == 3) {
            gcol[nt] = g.gamma[nt * 16 + c];
            becol[nt] = g.beta[nt * 16 + c];
        }
    }

#pragma unroll
    for (int r = 0; r < 4; ++r) {
        int grow = row0 + wave * 16 + q * 4 + r;
        float v[8];
#pragma unroll
        for (int nt = 0; nt < 8; ++nt) v[nt] = acc[nt][r] + bcol[nt];
        if constexpr (EPI == 3) {
            float s = 0.f, ss = 0.f;
#pragma unroll
            for (int nt = 0; nt < 8; ++nt) { s += v[nt]; ss += v[nt] * v[nt]; }
#pragma unroll
            for (int m = 8; m >= 1; m >>= 1) {
                s += __shfl_xor(s, m, 64);
                ss += __shfl_xor(ss, m, 64);
            }
            float mu = s * (1.f / 128.f);
            float var = ss * (1.f / 128.f) - mu * mu;
            float rs = rsqrtf(var + 1e-5f);
#pragma unroll
            for (int nt = 0; nt < 8; ++nt)
                v[nt] = fmaxf((v[nt] - mu) * rs * gcol[nt] + becol[nt], 0.f);
        }
        if (g.aMode > 0) {
            float pa[8];
#pragma unroll
            for (int i = 0; i < 8; ++i) pa[i] = 0.f;
#pragma unroll
            for (int nt = 0; nt < 8; ++nt) {
                int col = nt * 16 + c;
                float2 w0 = *(const float2*)&g.wav0[col * 2];
                pa[0] += v[nt] * w0.x; pa[1] += v[nt] * w0.y;
                if (g.aMode > 1) {
                    float2 w1 = *(const float2*)&g.wav1[col * 2];
                    pa[2] += v[nt] * w1.x; pa[3] += v[nt] * w1.y;
                }
                if (g.aMode > 2) {
                    float2 w2 = *(const float2*)&g.wav2[col * 2];
                    float2 w3 = *(const float2*)&g.wav3[col * 2];
                    pa[4] += v[nt] * w2.x; pa[5] += v[nt] * w2.y;
                    pa[6] += v[nt] * w3.x; pa[7] += v[nt] * w3.y;
                }
            }
#pragma unroll
            for (int m = 8; m >= 1; m >>= 1) {
                pa[0] += __shfl_xor(pa[0], m, 64); pa[1] += __shfl_xor(pa[1], m, 64);
                pa[2] += __shfl_xor(pa[2], m, 64); pa[3] += __shfl_xor(pa[3], m, 64);
                pa[4] += __shfl_xor(pa[4], m, 64); pa[5] += __shfl_xor(pa[5], m, 64);
                pa[6] += __shfl_xor(pa[6], m, 64); pa[7] += __shfl_xor(pa[7], m, 64);
            }
            if (c == 0 && grow < g.M) {
                float* ao = &g.aOut[(size_t)grow * g.aStride];
                ao[0] = pa[0]; ao[1] = pa[1];
                if (g.aMode > 1) { ao[2] = pa[2]; ao[3] = pa[3]; }
                if (g.aMode > 2) { ao[4] = pa[4]; ao[5] = pa[5]; ao[6] = pa[6]; ao[7] = pa[7]; }
            }
        }
        if (grow < g.M) {
            unsigned short* Y = (unsigned short*)g.Y;
#pragma unroll
            for (int nt = 0; nt < 8; ++nt)
                Y[(size_t)grow * g.ldY + nt * 16 + c] = f2bf(v[nt]);
        }
    }
}

// ---------------------------------------------------------------------------
// D2a: tiny bucket scan (1 block) — between prep(hist) and the merged dispatch
// ---------------------------------------------------------------------------
__global__ __launch_bounds__(256) void k_scan(
    const int* __restrict__ bcnt, int* __restrict__ bukoff, int* __restrict__ bukcur) {
    __shared__ int sd[256];
    int t = threadIdx.x;
    int i0 = t * 4;
    int v0 = (i0 < NBUK) ? bcnt[i0] : 0;
    int v1 = (i0 + 1 < NBUK) ? bcnt[i0 + 1] : 0;
    int v2 = (i0 + 2 < NBUK) ? bcnt[i0 + 2] : 0;
    int v3 = (i0 + 3 < NBUK) ? bcnt[i0 + 3] : 0;
    int csum = v0 + v1 + v2 + v3;
    sd[t] = csum;
    __syncthreads();
    for (int off = 1; off < 256; off <<= 1) {
        int tmp = (t >= off) ? sd[t - off] : 0;
        __syncthreads();
        sd[t] += tmp;
        __syncthreads();
    }
    int excl = sd[t] - csum;
    int p0 = excl, p1 = excl + v0, p2 = excl + v0 + v1, p3 = excl + v0 + v1 + v2;
    if (i0 < NBUK) { bukoff[i0] = p0; bukcur[i0] = p0; }
    if (i0 + 1 < NBUK) { bukoff[i0 + 1] = p1; bukcur[i0 + 1] = p1; }
    if (i0 + 2 < NBUK) { bukoff[i0 + 2] = p2; bukcur[i0 + 2] = p2; }
    if (i0 + 3 < NBUK) { bukoff[i0 + 3] = p3; bukcur[i0 + 3] = p3; }
    if (t == 0) bukoff[NBUK] = ETOT;
}

// ---------------------------------------------------------------------------
// D2b: lin0 GEMM (async-staged) blocks + scatter blocks merged in one grid.
// ---------------------------------------------------------------------------
__global__ __launch_bounds__(256) void k_lin0_scat(
    GPair P, int gemmBlocks,
    const int* __restrict__ js_src, const int* __restrict__ js_dst,
    const int* __restrict__ sj_src, const int* __restrict__ sj_dst,
    const int* __restrict__ ss_src, const int* __restrict__ ss_dst,
    int* __restrict__ bukcur, uint2* __restrict__ pairs) {
    if (blockIdx.x < (unsigned)gemmBlocks) {
        mgemm_body<3>(P, blockIdx.x);
        return;
    }
    __shared__ int lh[NBUK];
    __shared__ int lbase[NBUK];
    int t = threadIdx.x;
    int sb = blockIdx.x - gemmBlocks;
    const int CH = (ETOT + SCAT_NB - 1) / SCAT_NB;
    const int beg = sb * CH;
    const int endi = (beg + CH < ETOT) ? beg + CH : ETOT;
    if (beg >= ETOT) return;
    for (int i = t; i < NBUK; i += 256) lh[i] = 0;
    __syncthreads();
    for (int e = beg + t; e < endi; e += 256) {
        int src, bin;
        edge_decode(e, js_src, js_dst, sj_src, sj_dst, ss_src, ss_dst, src, bin);
        atomicAdd(&lh[bin >> 6], 1);
    }
    __syncthreads();
    for (int i = t; i < NBUK; i += 256) {
        int v = lh[i];
        lbase[i] = v ? atomicAdd(&bukcur[i], v) : 0;
    }
    __syncthreads();
    for (int i = t; i < NBUK; i += 256) lh[i] = 0;
    __syncthreads();
    for (int e = beg + t; e < endi; e += 256) {
        int src, bin;
        edge_decode(e, js_src, js_dst, sj_src, sj_dst, ss_src, ss_dst, src, bin);
        int bu = bin >> 6;
        int pos = lbase[bu] + atomicAdd(&lh[bu], 1);
        pairs[pos] = make_uint2((unsigned)src, (unsigned)bin);
    }
}

// ---------------------------------------------------------------------------
// D4: finalize — one block per bucket, dense contiguous esrc writes
// ---------------------------------------------------------------------------
__global__ __launch_bounds__(256) void k_finalize(
    const uint2* __restrict__ pairs, const int* __restrict__ bukoff,
    int* __restrict__ offs, int* __restrict__ esrc) {
    int b = blockIdx.x, t = threadIdx.x;
    int base = bukoff[b], endi = bukoff[b + 1];
    __shared__ int cnt[64], excl[64], curs[64];
    if (t < 64) cnt[t] = 0;
    __syncthreads();
    for (int i = base + t; i < endi; i += 256)
        atomicAdd(&cnt[pairs[i].y & 63], 1);
    __syncthreads();
    if (t < 64) {
        int v = cnt[t];
        int inc = v;
#pragma unroll
        for (int off = 1; off < 64; off <<= 1) {
            int tmp = __shfl_up(inc, off, 64);
            if (t >= off) inc += tmp;
        }
        excl[t] = inc - v;
        curs[t] = inc - v;
    }
    __syncthreads();
    for (int i = base + t; i < endi; i += 256) {
        uint2 p = pairs[i];
        int lb = p.y & 63;
        int pos = atomicAdd(&curs[lb], 1);
        esrc[base + pos] = (int)p.x;
    }
    if (t < 64) {
        int bin = b * 64 + t;
        if (bin < NBINS) offs[bin] = base + excl[t];
    }
    if (b == 0 && t == 0) offs[NBINS] = ETOT;
}

// ---------------------------------------------------------------------------
// Gather v5: deferred projection. Aggregates 128-dim SOURCE features.
// Quarter-wave (16 lanes) per edge, lane = 8 cols (uint4), both heads from one
// row read. Reduce via shfl_xor {16,32}.
// ---------------------------------------------------------------------------
__device__ inline void fm8(float p0, float p1, uint4 u, float a0[8], float a1[8]) {
    float x0 = __uint_as_float(u.x << 16);
    float x1 = __uint_as_float(u.x & 0xffff0000u);
    float x2 = __uint_as_float(u.y << 16);
    float x3 = __uint_as_float(u.y & 0xffff0000u);
    float x4 = __uint_as_float(u.z << 16);
    float x5 = __uint_as_float(u.z & 0xffff0000u);
    float x6 = __uint_as_float(u.w << 16);
    float x7 = __uint_as_float(u.w & 0xffff0000u);
    a0[0] += p0 * x0; a0[1] += p0 * x1; a0[2] += p0 * x2; a0[3] += p0 * x3;
    a0[4] += p0 * x4; a0[5] += p0 * x5; a0[6] += p0 * x6; a0[7] += p0 * x7;
    a1[0] += p1 * x0; a1[1] += p1 * x1; a1[2] += p1 * x2; a1[3] += p1 * x3;
    a1[4] += p1 * x4; a1[5] += p1 * x5; a1[6] += p1 * x6; a1[7] += p1 * x7;
}

__device__ inline void rel_run(
    const int* __restrict__ esrc, int beg, int end,
    const float* __restrict__ aSrc, int aShift, int aOff, float adx, float ady,
    const unsigned short* __restrict__ rows, int colOff, int g,
    float a0[8], float a1[8], float& den0, float& den1) {
    int j = beg;
    for (; j + 8 <= end; j += 8) {
        int s0 = esrc[j + g];
        int s1 = esrc[j + 4 + g];
        uint4 u0 = *(const uint4*)&rows[(unsigned)s0 * 128 + colOff];
        uint4 u1 = *(const uint4*)&rows[(unsigned)s1 * 128 + colOff];
        float2 f0 = *(const float2*)&aSrc[((unsigned)s0 << aShift) + aOff];
        float2 f1 = *(const float2*)&aSrc[((unsigned)s1 << aShift) + aOff];
        float e00 = f0.x + adx; e00 = e00 > 0.f ? e00 : 0.2f * e00;
        float e01 = f0.y + ady; e01 = e01 > 0.f ? e01 : 0.2f * e01;
        float e10 = f1.x + adx; e10 = e10 > 0.f ? e10 : 0.2f * e10;
        float e11 = f1.y + ady; e11 = e11 > 0.f ? e11 : 0.2f * e11;
        float p00 = __expf(e00), p01 = __expf(e01);
        float p10 = __expf(e10), p11 = __expf(e11);
        fm8(p00, p01, u0, a0, a1);
        fm8(p10, p11, u1, a0, a1);
        den0 += p00 + p10; den1 += p01 + p11;
    }
    for (; j < end; j += 4) {
        int e = j + g;
        bool ok = e < end;
        int s = esrc[ok ? e : j];
        uint4 u = *(const uint4*)&rows[(unsigned)s * 128 + colOff];
        float2 f = *(const float2*)&aSrc[((unsigned)s << aShift) + aOff];
        float e0 = f.x + adx; e0 = e0 > 0.f ? e0 : 0.2f * e0;
        float e1 = f.y + ady; e1 = e1 > 0.f ? e1 : 0.2f * e1;
        float p0 = ok ? __expf(e0) : 0.f;
        float p1 = ok ? __expf(e1) : 0.f;
        fm8(p0, p1, u, a0, a1);
        den0 += p0; den1 += p1;
    }
}

__device__ inline void store8(unsigned short* dst, const float v[8]) {
    uint4 o;
    o.x = (unsigned)f2bf(v[0]) | ((unsigned)f2bf(v[1]) << 16);
    o.y = (unsigned)f2bf(v[2]) | ((unsigned)f2bf(v[3]) << 16);
    o.z = (unsigned)f2bf(v[4]) | ((unsigned)f2bf(v[5]) << 16);
    o.w = (unsigned)f2bf(v[6]) | ((unsigned)f2bf(v[7]) << 16);
    *(uint4*)dst = o;
}

__device__ inline void finish_store(float a0[8], float a1[8], float den0, float den1,
                                    int lane, unsigned short* base) {
    float d0 = den0; d0 += __shfl_xor(d0, 16, 64); d0 += __shfl_xor(d0, 32, 64);
    float d1 = den1; d1 += __shfl_xor(d1, 16, 64); d1 += __shfl_xor(d1, 32, 64);
    float s0 = 1.f / (d0 + 1e-16f), s1 = 1.f / (d1 + 1e-16f);
    float o0[8], o1[8];
#pragma unroll
    for (int i = 0; i < 8; ++i) {
        float t0 = a0[i]; t0 += __shfl_xor(t0, 16, 64); t0 += __shfl_xor(t0, 32, 64);
        float t1 = a1[i]; t1 += __shfl_xor(t1, 16, 64); t1 += __shfl_xor(t1, 32, 64);
        o0[i] = t0 * s0; o1[i] = t1 * s1;
    }
    if ((lane >> 4) == 0) {
        store8(base, o0);
        store8(base + 128, o1);
    }
}

__global__ __launch_bounds__(256) void k_gather_all(
    const int* __restrict__ offs, const int* __restrict__ esrc,
    const float* __restrict__ aJ, const float* __restrict__ aS,
    const unsigned short* __restrict__ rowsJ,   // job src rows (ld 128)
    const unsigned short* __restrict__ rowsS,   // skill src rows (ld 128)
    unsigned short* __restrict__ aggS,          // [NS][512]: jsH0|jsH1|ssH0|ssH1
    unsigned short* __restrict__ aggJ,          // [NJ][256]: sjH0|sjH1
    int jobOnly) {
    int wave = threadIdx.x >> 6, lane = threadIdx.x & 63;
    int idx = blockIdx.x * 4 + wave;
    int g = lane >> 4, cl = lane & 15;
    int colOff = cl * 8;

    float a0[8], a1[8], den0, den1;

    if (jobOnly) {
        if (idx >= NJ) return;
        int d = idx;
#pragma unroll
        for (int i = 0; i < 8; ++i) { a0[i] = 0.f; a1[i] = 0.f; }
        den0 = den1 = 0.f;
        int bb = NS + d;
        float2 ad = *(const float2*)&aJ[(unsigned)d * 4 + 2];
        rel_run(esrc, offs[bb], offs[bb + 1], aS, 3, 4, ad.x, ad.y, rowsS, colOff, g, a0, a1, den0, den1);
        finish_store(a0, a1, den0, den1, lane, &aggJ[(size_t)d * 256 + colOff]);
        return;
    }
    if (idx < NS) {
        int d = idx;
#pragma unroll
        for (int i = 0; i < 8; ++i) { a0[i] = 0.f; a1[i] = 0.f; }
        den0 = den1 = 0.f;
        float2 adA = *(const float2*)&aS[(unsigned)d * 8 + 2];
        rel_run(esrc, offs[d], offs[d + 1], aJ, 2, 0, adA.x, adA.y, rowsJ, colOff, g, a0, a1, den0, den1);
        finish_store(a0, a1, den0, den1, lane, &aggS[(size_t)d * 512 + colOff]);
#pragma unroll
        for (int i = 0; i < 8; ++i) { a0[i] = 0.f; a1[i] = 0.f; }
        den0 = den1 = 0.f;
        int bb = NS + NJ + d;
        float2 adB = *(const float2*)&aS[(unsigned)d * 8 + 6];
        rel_run(esrc, offs[bb], offs[bb + 1], aS, 3, 0, adB.x, adB.y, rowsS, colOff, g, a0, a1, den0, den1);
        finish_store(a0, a1, den0, den1, lane, &aggS[(size_t)d * 512 + 256 + colOff]);
    } else if (idx < NS + NJ) {
        int d = idx - NS;
#pragma unroll
        for (int i = 0; i < 8; ++i) { a0[i] = 0.f; a1[i] = 0.f; }
        den0 = den1 = 0.f;
        int bb = NS + d;
        float2 ad = *(const float2*)&aJ[(unsigned)d * 4 + 2];
        rel_run(esrc, offs[bb], offs[bb + 1], aS, 3, 4, ad.x, ad.y, rowsS, colOff, g, a0, a1, den0, den1);
        finish_store(a0, a1, den0, den1, lane, &aggJ[(size_t)d * 256 + colOff]);
    }
}

// ---------------------------------------------------------------------------
// D6: two-stage fused GEMM, LDS-lean. Per np half (128 cols of stage1 out):
// stage1 K-loop -> Y1l[4] (half), then stage2 K-slice accumulates into acc2
// registers. LDS = Al(5K)+Bl(10K)+Y1l(20.5K) = 35.8KB -> 4 blocks/CU.
// ---------------------------------------------------------------------------
struct FJob {
    const unsigned short* X; int K1; int M;
    const unsigned short* Wt1; const float* bias1;
    const unsigned short* Wt2; const float* bias2;
    const float* wa; float* aOut; int aStride;
    unsigned short* Y2;                          // nullable; ld 128
};
struct FPair { FJob a; FJob b; int blocksA; };

__global__ __launch_bounds__(256) void k_fused2(FPair P) {
    int mb = blockIdx.x;
    FJob g = (mb < P.blocksA) ? P.a : P.b;
    if (mb >= P.blocksA) mb -= P.blocksA;
    const int row0 = mb * 64;
    const int K1 = g.K1;

    __shared__ __align__(16) unsigned short Al[64][40];
    __shared__ __align__(16) unsigned short Bl[128][40];
    __shared__ __align__(16) unsigned short Y1l[4][64][40];
    const int t = threadIdx.x;
    const int wave = t >> 6, lane = t & 63;
    const int q = lane >> 4, c = lane & 15;

    f4_t acc2[8];
#pragma unroll
    for (int nt = 0; nt < 8; ++nt) acc2[nt] = (f4_t){0.f, 0.f, 0.f, 0.f};

    for (int np = 0; np < 2; ++np) {
        f4_t acc[8];
#pragma unroll
        for (int nt = 0; nt < 8; ++nt) acc[nt] = (f4_t){0.f, 0.f, 0.f, 0.f};
        for (int k0 = 0; k0 < K1; k0 += 32) {
#pragma unroll
            for (int it = 0; it < 3; ++it) {
                int idx = t + it * 256;
                int r = idx >> 2, cc = (idx & 3) * 8;
                if (r < 64) {
                    int gr = row0 + r;
                    uint4 va = (gr < g.M) ? *(const uint4*)&g.X[(size_t)gr * K1 + k0 + cc]
                                          : make_uint4(0u, 0u, 0u, 0u);
                    *(uint4*)&Al[r][cc] = va;
                } else {
                    int br = r - 64;
                    *(uint4*)&Bl[br][cc] = *(const uint4*)&g.Wt1[(size_t)(np * 128 + br) * K1 + k0 + cc];
                }
            }
            __syncthreads();
            bf8_t af = *(const bf8_t*)&Al[wave * 16 + c][q * 8];
#pragma unroll
            for (int nt = 0; nt < 8; ++nt) {
                bf8_t bfr = *(const bf8_t*)&Bl[nt * 16 + c][q * 8];
                acc[nt] = __builtin_amdgcn_mfma_f32_16x16x32_bf16(af, bfr, acc[nt], 0, 0, 0);
            }
            __syncthreads();
        }
        float bcol[8];
#pragma unroll
        for (int nt = 0; nt < 8; ++nt) bcol[nt] = g.bias1[np * 128 + nt * 16 + c];
#pragma unroll
        for (int r = 0; r < 4; ++r) {
            int row = wave * 16 + q * 4 + r;
#pragma unroll
            for (int nt = 0; nt < 8; ++nt)
                Y1l[nt >> 1][row][(nt & 1) * 16 + c] = f2bf(acc[nt][r] + bcol[nt]);
        }
        __syncthreads();
        // stage2 partial: K-slice np*128 .. np*128+127
        for (int k0 = 0; k0 < 128; k0 += 32) {
#pragma unroll
            for (int it = 0; it < 2; ++it) {
                int idx = t + it * 256;
                int br = idx >> 2, cc = (idx & 3) * 8;
                *(uint4*)&Bl[br][cc] = *(const uint4*)&g.Wt2[(size_t)br * 256 + np * 128 + k0 + cc];
            }
            __syncthreads();
            bf8_t af = *(const bf8_t*)&Y1l[k0 >> 5][wave * 16 + c][q * 8];
#pragma unroll
            for (int nt = 0; nt < 8; ++nt) {
                bf8_t bfr = *(const bf8_t*)&Bl[nt * 16 + c][q * 8];
                acc2[nt] = __builtin_amdgcn_mfma_f32_16x16x32_bf16(af, bfr, acc2[nt], 0, 0, 0);
            }
            __syncthreads();
        }
    }

    float b2[8];
#pragma unroll
    for (int nt = 0; nt < 8; ++nt) b2[nt] = g.bias2[nt * 16 + c];
#pragma unroll
    for (int r = 0; r < 4; ++r) {
        int grow = row0 + wave * 16 + q * 4 + r;
        float v[8];
#pragma unroll
        for (int nt = 0; nt < 8; ++nt) v[nt] = fmaxf(acc2[nt][r] + b2[nt], 0.f);
        if (g.wa) {
            float pa0 = 0.f, pa1 = 0.f;
#pragma unroll
            for (int nt = 0; nt < 8; ++nt) {
                float2 w0 = *(const float2*)&g.wa[(nt * 16 + c) * 2];
                pa0 += v[nt] * w0.x; pa1 += v[nt] * w0.y;
            }
#pragma unroll
            for (int m = 8; m >= 1; m >>= 1) {
                pa0 += __shfl_xor(pa0, m, 64);
                pa1 += __shfl_xor(pa1, m, 64);
            }
            if (c == 0 && grow < g.M) {
                g.aOut[(size_t)grow * g.aStride + 0] = pa0;
                g.aOut[(size_t)grow * g.aStride + 1] = pa1;
            }
        }
        if (g.Y2 && grow < g.M) {
#pragma unroll
            for (int nt = 0; nt < 8; ++nt)
                g.Y2[(size_t)grow * 128 + nt * 16 + c] = f2bf(v[nt]);
        }
    }
}

// ---------------------------------------------------------------------------
// D8: three-stage fused GEMM, LDS-lean. Same np-interleave as k_fused2; the
// Yl buffer is reused for stage2's output (stage3 input). 35.8KB LDS.
// ---------------------------------------------------------------------------
struct F3 {
    const unsigned short* X; int M;
    const unsigned short* Wt1; const float* bias1;
    const unsigned short* Wt2; const float* bias2;
    const unsigned short* Wt3; const float* bias3;
    const float* qv; float* sc; float* Y;
};

__global__ __launch_bounds__(256) void k_fused3(F3 g) {
    int mb = blockIdx.x;
    const int row0 = mb * 64;
    __shared__ __align__(16) unsigned short Al[64][40];
    __shared__ __align__(16) unsigned short Bl[128][40];
    __shared__ __align__(16) unsigned short Yl[4][64][40];
    const int t = threadIdx.x;
    const int wave = t >> 6, lane = t & 63;
    const int q = lane >> 4, c = lane & 15;

    f4_t acc2[8];
#pragma unroll
    for (int nt = 0; nt < 8; ++nt) acc2[nt] = (f4_t){0.f, 0.f, 0.f, 0.f};

    for (int np = 0; np < 2; ++np) {
        f4_t acc[8];
#pragma unroll
        for (int nt = 0; nt < 8; ++nt) acc[nt] = (f4_t){0.f, 0.f, 0.f, 0.f};
        for (int k0 = 0; k0 < 256; k0 += 32) {
#pragma unroll
            for (int it = 0; it < 3; ++it) {
                int idx = t + it * 256;
                int r = idx >> 2, cc = (idx & 3) * 8;
                if (r < 64) {
                    int gr = row0 + r;
                    uint4 va = (gr < g.M) ? *(const uint4*)&g.X[(size_t)gr * 256 + k0 + cc]
                                          : make_uint4(0u, 0u, 0u, 0u);
                    *(uint4*)&Al[r][cc] = va;
                } else {
                    int br = r - 64;
                    *(uint4*)&Bl[br][cc] = *(const uint4*)&g.Wt1[(size_t)(np * 128 + br) * 256 + k0 + cc];
                }
            }
            __syncthreads();
            bf8_t af = *(const bf8_t*)&Al[wave * 16 + c][q * 8];
#pragma unroll
            for (int nt = 0; nt < 8; ++nt) {
                bf8_t bfr = *(const bf8_t*)&Bl[nt * 16 + c][q * 8];
                acc[nt] = __builtin_amdgcn_mfma_f32_16x16x32_bf16(af, bfr, acc[nt], 0, 0, 0);
            }
            __syncthreads();
        }
        float bcol[8];
#pragma unroll
        for (int nt = 0; nt < 8; ++nt) bcol[nt] = g.bias1[np * 128 + nt * 16 + c];
#pragma unroll
        for (int r = 0; r < 4; ++r) {
            int row = wave * 16 + q * 4 + r;
#pragma unroll
            for (int nt = 0; nt < 8; ++nt)
                Yl[nt >> 1][row][(nt & 1) * 16 + c] = f2bf(acc[nt][r] + bcol[nt]);
        }
        __syncthreads();
        for (int k0 = 0; k0 < 128; k0 += 32) {
#pragma unroll
            for (int it = 0; it < 2; ++it) {
                int idx = t + it * 256;
                int br = idx >> 2, cc = (idx & 3) * 8;
                *(uint4*)&Bl[br][cc] = *(const uint4*)&g.Wt2[(size_t)br * 256 + np * 128 + k0 + cc];
            }
            __syncthreads();
            bf8_t af = *(const bf8_t*)&Yl[k0 >> 5][wave * 16 + c][q * 8];
#pragma unroll
            for (int nt = 0; nt < 8; ++nt) {
                bf8_t bfr = *(const bf8_t*)&Bl[nt * 16 + c][q * 8];
                acc2[nt] = __builtin_amdgcn_mfma_f32_16x16x32_bf16(af, bfr, acc2[nt], 0, 0, 0);
            }
            __syncthreads();
        }
    }

    // stage2 epilogue: bias + relu -> Yl (reused; prior contents fully consumed)
    {
        float b2[8];
#pragma unroll
        for (int nt = 0; nt < 8; ++nt) b2[nt] = g.bias2[nt * 16 + c];
#pragma unroll
        for (int r = 0; r < 4; ++r) {
            int row = wave * 16 + q * 4 + r;
#pragma unroll
            for (int nt = 0; nt < 8; ++nt)
                Yl[nt >> 1][row][(nt & 1) * 16 + c] = f2bf(fmaxf(acc2[nt][r] + b2[nt], 0.f));
        }
        __syncthreads();
    }

    // stage3: 128 -> 128, f32 out + scores
    f4_t acc3[8];
#pragma unroll
    for (int nt = 0; nt < 8; ++nt) acc3[nt] = (f4_t){0.f, 0.f, 0.f, 0.f};
    for (int k0 = 0; k0 < 128; k0 += 32) {
#pragma unroll
        for (int it = 0; it < 2; ++it) {
            int idx = t + it * 256;
            int br = idx >> 2, cc = (idx & 3) * 8;
            *(uint4*)&Bl[br][cc] = *(const uint4*)&g.Wt3[(size_t)br * 128 + k0 + cc];
        }
        __syncthreads();
        bf8_t af = *(const bf8_t*)&Yl[k0 >> 5][wave * 16 + c][q * 8];
#pragma unroll
        for (int nt = 0; nt < 8; ++nt) {
            bf8_t bfr = *(const bf8_t*)&Bl[nt * 16 + c][q * 8];
            acc3[nt] = __builtin_amdgcn_mfma_f32_16x16x32_bf16(af, bfr, acc3[nt], 0, 0, 0);
        }
        __syncthreads();
    }
    float b3[8], qcol[8];
#pragma unroll
    for (int nt = 0; nt < 8; ++nt) {
        b3[nt] = g.bias3[nt * 16 + c];
        qcol[nt] = g.qv[nt * 16 + c];
    }
#pragma unroll
    for (int r = 0; r < 4; ++r) {
        int grow = row0 + wave * 16 + q * 4 + r;
        float v[8];
#pragma unroll
        for (int nt = 0; nt < 8; ++nt) v[nt] = acc3[nt][r] + b3[nt];
        float part = 0.f;
#pragma unroll
        for (int nt = 0; nt < 8; ++nt) part += v[nt] * qcol[nt];
#pragma unroll
        for (int m = 8; m >= 1; m >>= 1) part += __shfl_xor(part, m, 64);
        if (grow < g.M) {
            if (c == 0) g.sc[grow] = part;
#pragma unroll
            for (int nt = 0; nt < 8; ++nt)
                g.Y[(size_t)grow * 128 + nt * 16 + c] = v[nt];
        }
    }
}

// ---------------------------------------------------------------------------
extern "C" void kernel_launch(void* const* d_in, const int* in_sizes, int n_in,
                              void* d_out, int out_size, void* d_ws, size_t ws_size,
                              hipStream_t stream) {
    const float* x_job   = (const float*)d_in[0];
    const float* x_skill = (const float*)d_in[1];
    const int* js_src = (const int*)d_in[2];
    const int* js_dst = (const int*)d_in[3];
    const int* sj_src = (const int*)d_in[4];
    const int* sj_dst = (const int*)d_in[5];
    const int* ss_src = (const int*)d_in[6];
    const int* ss_dst = (const int*)d_in[7];
    const float* query    = (const float*)d_in[8];
    const float* W0_job   = (const float*)d_in[9];
    const float* b0_job   = (const float*)d_in[10];
    const float* g0_job   = (const float*)d_in[11];
    const float* be0_job  = (const float*)d_in[12];
    const float* W0_skill = (const float*)d_in[13];
    const float* b0_skill = (const float*)d_in[14];
    const float* g0_skill = (const float*)d_in[15];
    const float* be0_skill= (const float*)d_in[16];
    const float* gat_Ws = (const float*)d_in[17];
    const float* gat_Wd = (const float*)d_in[18];
    const float* gat_as = (const float*)d_in[19];
    const float* gat_ad = (const float*)d_in[20];
    const float* gat_b  = (const float*)d_in[21];
    const float* inter_W = (const float*)d_in[22];
    const float* inter_b = (const float*)d_in[23];
    const float* Wjf = (const float*)d_in[24];
    const float* bjf = (const float*)d_in[25];
    const float* Wq  = (const float*)d_in[26];
    const float* bq  = (const float*)d_in[27];

    char* w = (char*)d_ws;
    auto alloc = [&](size_t bytes) -> void* {
        void* p = (void*)w;
        w += (bytes + 255) & ~(size_t)255;
        return p;
    };
    u16* xj   = (u16*)alloc((size_t)NJ * 128 * 2);
    u16* xs   = (u16*)alloc((size_t)NS * 128 * 2);
    u16* xs1  = (u16*)alloc((size_t)NS * 128 * 2);
    u16* aggJ  = (u16*)alloc((size_t)NJ * 256 * 2);
    u16* aggJ1 = (u16*)alloc((size_t)NJ * 256 * 2);
    u16* aggS  = (u16*)alloc((size_t)NS * 512 * 2);
    u16* WtW0j = (u16*)alloc((size_t)SBERT * 128 * 2);
    u16* WtW0s = (u16*)alloc((size_t)SBERT * 128 * 2);
    u16* WsS1  = (u16*)alloc((size_t)256 * 512 * 2);
    u16* WsJ0  = (u16*)alloc((size_t)256 * 256 * 2);
    u16* WsJ1  = (u16*)alloc((size_t)256 * 256 * 2);
    u16* WtI00 = (u16*)alloc((size_t)128 * 256 * 2);
    u16* WtI01 = (u16*)alloc((size_t)128 * 256 * 2);
    u16* WtI10 = (u16*)alloc((size_t)128 * 256 * 2);
    u16* WtJf  = (u16*)alloc((size_t)128 * 128 * 2);
    float* gbS = (float*)alloc(256 * 4);
    float* aJ = (float*)alloc((size_t)NJ * 4 * 4);
    float* aS = (float*)alloc((size_t)NS * 8 * 4);
    float* wsa = (float*)alloc(6 * 256 * 4);
    float* wda = (float*)alloc(6 * 256 * 4);
    int* bcnt   = (int*)alloc((size_t)NBUK * 4);
    int* bukoff = (int*)alloc((size_t)(NBUK + 1) * 4);
    int* bukcur = (int*)alloc((size_t)NBUK * 4);
    uint2* pairs = (uint2*)alloc((size_t)ETOT * 8);
    int* offs = (int*)alloc((size_t)(NBINS + 1) * 4);
    int* esrc = (int*)alloc((size_t)ETOT * 4);

    float* out = (float*)d_out;
    float* scores  = out;
    float* job_emb = out + NJ;
    float* qv      = out + NJ + (size_t)NJ * 128;

    const int mbJ = cdiv(NJ, 64);   // 469
    const int mbS = cdiv(NS, 64);   // 188
    const int gemmB = mbJ + mbS;    // 657

    // M0: zero bucket counters + structured weight buffers (block layouts)
    hipMemsetAsync(bcnt, 0, (size_t)NBUK * 4, stream);
    hipMemsetAsync(WsS1, 0, (size_t)256 * 512 * 2, stream);
    hipMemsetAsync(WsJ0, 0, (size_t)256 * 256 * 2, stream);
    hipMemsetAsync(WsJ1, 0, (size_t)256 * 256 * 2, stream);

    // D1: prep (weight casts/structured layouts + wa + qvec + gbS + hist)
    {
        const size_t WS = (size_t)128 * 256;
        const size_t IW = (size_t)256 * 128;
        PrepArgs A;
        A.m[0]  = {W0_job,   WtW0j, SBERT, 128, 128, SBERT};
        A.m[1]  = {W0_skill, WtW0s, SBERT, 128, 128, SBERT};
        // WsS1 (256x512): [n<128,k<128]=Ws00[:,:128]; [n>=128,k 128..256)=Ws00[:,128:]
        //                 [n<128,k 256..384)=Ws02[:,:128]; [n>=128,k 384..512)=Ws02[:,128:]
        A.m[2]  = {gat_Ws + 0 * WS,       WsS1,                       128, 128, 256, 512};
        A.m[3]  = {gat_Ws + 0 * WS + 128, WsS1 + 128 * 512 + 128,     128, 128, 256, 512};
        A.m[4]  = {gat_Ws + 2 * WS,       WsS1 + 256,                 128, 128, 256, 512};
        A.m[5]  = {gat_Ws + 2 * WS + 128, WsS1 + 128 * 512 + 384,     128, 128, 256, 512};
        // WsJ0 (256x256): block-diag from Ws01
        A.m[6]  = {gat_Ws + 1 * WS,       WsJ0,                       128, 128, 256, 256};
        A.m[7]  = {gat_Ws + 1 * WS + 128, WsJ0 + 128 * 256 + 128,     128, 128, 256, 256};
        // WsJ1 (256x256): block-diag from Ws11
        A.m[8]  = {gat_Ws + 4 * WS,       WsJ1,                       128, 128, 256, 256};
        A.m[9]  = {gat_Ws + 4 * WS + 128, WsJ1 + 128 * 256 + 128,     128, 128, 256, 256};
        A.m[10] = {inter_W + 0 * IW, WtI00, 256, 128, 128, 256};
        A.m[11] = {inter_W + 1 * IW, WtI01, 256, 128, 128, 256};
        A.m[12] = {inter_W + 2 * IW, WtI10, 256, 128, 128, 256};
        A.m[13] = {Wjf, WtJf, 128, 128, 128, 128};
        A.Ws = gat_Ws; A.as_ = gat_as; A.Wd = gat_Wd; A.ad_ = gat_ad;
        A.wsa = wsa; A.wda = wda; A.bcnt = bcnt;
        A.query = query; A.Wq = Wq; A.bq = bq; A.qv = qv;
        A.gat_b = gat_b; A.gbS = gbS;
        A.js_src = js_src; A.js_dst = js_dst;
        A.sj_src = sj_src; A.sj_dst = sj_dst;
        A.ss_src = ss_src; A.ss_dst = ss_dst;
        k_prep<<<PREP_HIST + HIST_NB, 256, 0, stream>>>(A);
    }

    // D2a: bucket scan (1 block)
    k_scan<<<1, 256, 0, stream>>>(bcnt, bukoff, bukcur);

    // D2b: lin0 GEMM (async gload_lds staging) + scatter blocks merged
    {
        GPair P;
        P.a = {x_job, WtW0j, b0_job, g0_job, be0_job, xj, NJ, SBERT, 128, 128, 1,
               nullptr, nullptr, 2, wsa + 0, wda + 256, nullptr, nullptr, aJ, 4};
        P.b = {x_skill, WtW0s, b0_skill, g0_skill, be0_skill, xs, NS, SBERT, 128, 128, 1,
               nullptr, nullptr, 4, wsa + 2 * 256, wda + 0, wsa + 1 * 256, wda + 2 * 256, aS, 8};
        P.blocksA = mbJ;
        k_lin0_scat<<<gemmB + SCAT_NB, 256, 0, stream>>>(
            P, gemmB, js_src, js_dst, sj_src, sj_dst, ss_src, ss_dst, bukcur, pairs);
    }

    // D4: finalize CSR
    k_finalize<<<NBUK, 256, 0, stream>>>(pairs, bukoff, offs, esrc);

    // D5: gather l0 — aggregate 128-dim source features (both heads)
    k_gather_all<<<cdiv(NS + NJ, 4), 256, 0, stream>>>(
        offs, esrc, aJ, aS, xj, xs, aggS, aggJ, 0);

    // D6: fused Ws-proj + inter (relu) + alpha-l1. Job: no Y2 store needed.
    {
        FPair P;
        P.a = {aggJ, 256, NJ, WsJ0, gat_b + 256, WtI00, inter_b + 0,
               wda + 4 * 256, aJ + 2, 4, nullptr};
        P.b = {aggS, 512, NS, WsS1, gbS, WtI01, inter_b + 128,
               wsa + 4 * 256, aS + 4, 8, xs1};
        P.blocksA = mbJ;
        k_fused2<<<gemmB, 256, 0, stream>>>(P);
    }

    // D7: gather l1 (job dsts only; srcs are xs1, 3MB working set)
    k_gather_all<<<cdiv(NJ, 4), 256, 0, stream>>>(
        offs, esrc, aJ, aS, nullptr, xs1, nullptr, aggJ1, 1);

    // D8: fused Ws-proj + inter(relu) + final projection + scores
    {
        F3 g3;
        g3.X = aggJ1; g3.M = NJ;
        g3.Wt1 = WsJ1; g3.bias1 = gat_b + 4 * 256;
        g3.Wt2 = WtI10; g3.bias2 = inter_b + 2 * 128;
        g3.Wt3 = WtJf; g3.bias3 = bjf;
        g3.qv = qv; g3.sc = scores; g3.Y = job_emb;
        k_fused3<<<gemmB, 256, 0, stream>>>(g3);
    }
}

// Round 14
// 328.283 us; speedup vs baseline: 1.4913x; 1.0547x over previous
//
#include <hip/hip_runtime.h>
#include <hip/hip_bf16.h>
#include <math.h>

#define NJ 30000
#define NS 12000
#define E_JS 300000
#define E_SJ 300000
#define E_SS 150000
#define ETOT (E_JS + E_SJ + E_SS + NS)   // 762000 incl. ss self loops
#define NBINS (NS + NJ + NS)             // 54000 combined dst bins
#define NBUK ((NBINS + 63) / 64)         // 844 coarse buckets
#define SBERT 384
#define HIST_NB 512
#define SCAT_NB 480
#define CAST_MATS 14
#define CAST_BPM 48
#define PREP_CAST (CAST_MATS * CAST_BPM)          // 672
#define PREP_WA   (PREP_CAST + 192)               // 864 (quarter-wave per output)
#define PREP_QV   PREP_WA                         // 864
#define PREP_GB   (PREP_QV + 1)                   // 865
#define PREP_HIST (PREP_GB + 1)                   // 866

static inline int cdiv(int a, int b) { return (a + b - 1) / b; }

typedef __attribute__((ext_vector_type(8))) short bf8_t;
typedef __attribute__((ext_vector_type(4))) float f4_t;
typedef unsigned short u16;

__device__ inline float bf2f(unsigned short u) {
    union { unsigned int i; float f; } z; z.i = ((unsigned int)u) << 16; return z.f;
}
__device__ inline unsigned short f2bf(float f) {
    unsigned int x = __float_as_uint(f);
    unsigned int r = (x + 0x7fffu + ((x >> 16) & 1u)) >> 16;   // RNE
    return (unsigned short)r;
}

// ---------------------------------------------------------------------------
// edge decode; bin layout: [0,NS) js | [NS,NS+NJ) sj | [NS+NJ,NBINS) ss+loops
// ---------------------------------------------------------------------------
__device__ inline void edge_decode(int e, const int* js_src, const int* js_dst,
                                   const int* sj_src, const int* sj_dst,
                                   const int* ss_src, const int* ss_dst,
                                   int& src, int& bin) {
    if (e < E_JS) { src = js_src[e]; bin = js_dst[e]; }
    else if (e < E_JS + E_SJ) { int i = e - E_JS; src = sj_src[i]; bin = NS + sj_dst[i]; }
    else if (e < E_JS + E_SJ + E_SS) { int i = e - E_JS - E_SJ; src = ss_src[i]; bin = NS + NJ + ss_dst[i]; }
    else { int i = e - E_JS - E_SJ - E_SS; src = i; bin = NS + NJ + i; }
}

// ---------------------------------------------------------------------------
// D1 k_prep: castT [0,672) | wa [672,864) | qvec [864] | gbS [865] | hist...
// bcnt / WsS1 / WsJ0 / WsJ1 zeroed by hipMemsetAsync before this dispatch.
// Generalized transposed cast: dst[n*dstLd + k] = bf16(src[k*srcLd + n]).
// wa: quarter-wave (16 lanes) per output — coalesced float4 dot + shfl reduce.
// ---------------------------------------------------------------------------
struct CastT { const float* src; unsigned short* dst; int K; int N; int srcLd; int dstLd; };
struct PrepArgs {
    CastT m[CAST_MATS];
    const float* Ws; const float* as_; const float* Wd; const float* ad_;
    float* wsa; float* wda; int* bcnt;
    const float* query; const float* Wq; const float* bq; float* qv;
    const float* gat_b; float* gbS;
    const int* js_src; const int* js_dst;
    const int* sj_src; const int* sj_dst;
    const int* ss_src; const int* ss_dst;
};

__global__ __launch_bounds__(256) void k_prep(PrepArgs A) {
    __shared__ float ldt[32][33];
    __shared__ int lh[NBUK];
    int b = blockIdx.x;
    if (b < PREP_CAST) {
        int mi = b / CAST_BPM, bx = b % CAST_BPM;
        CastT cm = A.m[mi];
        int tilesN = cm.N >> 5;
        int total = (cm.K >> 5) * tilesN;
        if (bx >= total) return;
        int tk = bx / tilesN, tn = bx % tilesN;
        int k0 = tk * 32, n0 = tn * 32;
        int col = threadIdx.x & 31;
        int row0 = threadIdx.x >> 5;
#pragma unroll
        for (int r = 0; r < 4; ++r) {
            int kk = row0 + r * 8;
            ldt[kk][col] = cm.src[(size_t)(k0 + kk) * cm.srcLd + n0 + col];
        }
        __syncthreads();
#pragma unroll
        for (int r = 0; r < 4; ++r) {
            int nn = row0 + r * 8;
            cm.dst[(size_t)(n0 + nn) * cm.dstLd + k0 + col] = f2bf(ldt[col][nn]);
        }
    } else if (b < PREP_WA) {
        int qw = ((b - PREP_CAST) * 256 + threadIdx.x) >> 4;   // quarter-wave id
        int cl = threadIdx.x & 15;
        if (qw < 2 * 1536) {
            int which = qw / 1536;
            int r = qw % 1536;
            int lr = r / 256;
            int kh = r % 256;
            int k = kh / 2, h = kh % 2;
            const float* W = which ? A.Wd : A.Ws;
            const float* a = which ? A.ad_ : A.as_;
            const float* wrow = W + ((size_t)(lr * 128 + k)) * 256 + h * 128 + cl * 8;
            const float* arow = a + (size_t)(lr * 2 + h) * 128 + cl * 8;
            float4 w0 = *(const float4*)wrow, w1 = *(const float4*)(wrow + 4);
            float4 a0 = *(const float4*)arow, a1 = *(const float4*)(arow + 4);
            float acc = w0.x * a0.x + w0.y * a0.y + w0.z * a0.z + w0.w * a0.w
                      + w1.x * a1.x + w1.y * a1.y + w1.z * a1.z + w1.w * a1.w;
            acc += __shfl_xor(acc, 1, 64);
            acc += __shfl_xor(acc, 2, 64);
            acc += __shfl_xor(acc, 4, 64);
            acc += __shfl_xor(acc, 8, 64);
            if (cl == 0) (which ? A.wda : A.wsa)[lr * 256 + k * 2 + h] = acc;
        }
    } else if (b == PREP_QV) {
        int c = threadIdx.x;
        if (c < 128) {
            float acc = A.bq[c];
            for (int k = 0; k < SBERT; ++k) acc += A.query[k] * A.Wq[(size_t)k * 128 + c];
            A.qv[c] = acc;
        }
    } else if (b == PREP_GB) {
        int c = threadIdx.x;
        if (c < 256) A.gbS[c] = A.gat_b[c] + A.gat_b[512 + c];   // gb(0,0)+gb(0,2)
    } else {
        int t = threadIdx.x;
        for (int i = t; i < NBUK; i += 256) lh[i] = 0;
        __syncthreads();
        int hb = b - PREP_HIST;
        for (int e = hb * 256 + t; e < ETOT; e += HIST_NB * 256) {
            int src, bin;
            edge_decode(e, A.js_src, A.js_dst, A.sj_src, A.sj_dst, A.ss_src, A.ss_dst, src, bin);
            atomicAdd(&lh[bin >> 6], 1);
        }
        __syncthreads();
        for (int i = t; i < NBUK; i += 256) {
            int v = lh[i];
            if (v) atomicAdd(&A.bcnt[i], v);
        }
    }
}

// ---------------------------------------------------------------------------
// MFMA GEMM body for D2 lin0 (fp32 X, K=384). BM=64, 4 waves x (16m x 128n).
// Async staging: global_load_lds width-16 into linear LDS, XOR-block-swizzled
// on the GLOBAL source; reads apply the same swizzle. ONE barrier per K-step;
// stage for tile k+1 issued right after the barrier, in flight through MFMA.
//   A: fp32 [64][32], 8x16B blocks/row, swz b^=(row&7); bf16-convert at read.
//   B: bf16 [128][32], 4x16B blocks/row, swz b^=((row>>1)&3).
// EPI 3: +bias,LN,relu->bf16, with alpha epilogue (aMode pairs).
// ---------------------------------------------------------------------------
struct GJob {
    const void* X; const unsigned short* Wt;
    const float* bias; const float* gamma; const float* beta;
    void* Y; int M; int K; int N; int ldY; int srcf32;
    const float* qv; float* sc;
    int aMode = 0;
    const float* wav0 = nullptr; const float* wav1 = nullptr;
    const float* wav2 = nullptr; const float* wav3 = nullptr;
    float* aOut = nullptr; int aStride = 0;
};
struct GPair { GJob a; GJob b; int blocksA; };

template <int EPI>
__device__ void mgemm_body(const GPair& P, int bx) {
    int mb = bx;
    GJob g = (mb < P.blocksA) ? P.a : P.b;
    if (mb >= P.blocksA) mb -= P.blocksA;
    const int row0 = mb * 64;

    __shared__ __align__(16) float As[2][64][32];           // 16 KB
    __shared__ __align__(16) unsigned short Bs[2][128][32]; // 16 KB
    const int t = threadIdx.x;
    const int wave = t >> 6, lane = t & 63;
    const int q = lane >> 4, c = lane & 15;
    const int K = g.K;
    const float* Xf = (const float*)g.X;

    f4_t acc[8];
#pragma unroll
    for (int nt = 0; nt < 8; ++nt) acc[nt] = (f4_t){0.f, 0.f, 0.f, 0.f};

    auto STAGE = [&](int cur, int k0) {
#pragma unroll
        for (int i = 0; i < 2; ++i) {
            int bi = i * 256 + t;
            int row = bi >> 3, b = bi & 7;
            int ra = row0 + row; ra = (ra < g.M) ? ra : (g.M - 1);
            const float* gsrc = Xf + (size_t)ra * K + k0 + ((b ^ (row & 7)) << 2);
            __builtin_amdgcn_global_load_lds(
                (__attribute__((address_space(1))) void*)gsrc,
                (__attribute__((address_space(3))) void*)((char*)&As[cur][0][0] + ((i * 4 + wave) << 10)),
                16, 0, 0);
        }
#pragma unroll
        for (int i = 0; i < 2; ++i) {
            int bi = i * 256 + t;
            int row = bi >> 2, b = bi & 3;
            const unsigned short* gsrc = g.Wt + (size_t)row * K + k0 + ((b ^ ((row >> 1) & 3)) << 3);
            __builtin_amdgcn_global_load_lds(
                (__attribute__((address_space(1))) void*)gsrc,
                (__attribute__((address_space(3))) void*)((char*)&Bs[cur][0][0] + ((i * 4 + wave) << 10)),
                16, 0, 0);
        }
    };

    auto MF = [&](int cur) {
        const char* Ab = (const char*)&As[cur][0][0];
        const char* Bb = (const char*)&Bs[cur][0][0];
        int r = wave * 16 + c;
        int sw = r & 7;
        f4_t fa0 = *(const f4_t*)(Ab + r * 128 + (((q * 2) ^ sw) << 4));
        f4_t fa1 = *(const f4_t*)(Ab + r * 128 + (((q * 2 + 1) ^ sw) << 4));
        bf8_t af;
        af[0] = (short)f2bf(fa0[0]); af[1] = (short)f2bf(fa0[1]);
        af[2] = (short)f2bf(fa0[2]); af[3] = (short)f2bf(fa0[3]);
        af[4] = (short)f2bf(fa1[0]); af[5] = (short)f2bf(fa1[1]);
        af[6] = (short)f2bf(fa1[2]); af[7] = (short)f2bf(fa1[3]);
#pragma unroll
        for (int nt = 0; nt < 8; ++nt) {
            int rb = nt * 16 + c;
            bf8_t bfr = *(const bf8_t*)(Bb + rb * 64 + ((q ^ ((rb >> 1) & 3)) << 4));
            acc[nt] = __builtin_amdgcn_mfma_f32_16x16x32_bf16(af, bfr, acc[nt], 0, 0, 0);
        }
    };

    STAGE(0, 0);
    int cur = 0;
    for (int k0 = 0; k0 < K; k0 += 32) {
        asm volatile("s_waitcnt vmcnt(0)" ::: "memory");
        __syncthreads();              // buf[cur] staged by all waves; prior reads done
        if (k0 + 32 < K) STAGE(cur ^ 1, k0 + 32);   // in flight through MF below
        MF(cur);
        cur ^= 1;
    }

    float bcol[8], gcol[8], becol[8];
#pragma unroll
    for (int nt = 0; nt < 8; ++nt) {
        bcol[nt] = g.bias[nt * 16 + c];
        if constexpr (EPI == 3) {
            gcol[nt] = g.gamma[nt * 16 + c];
            becol[nt] = g.beta[nt * 16 + c];
        }
    }

#pragma unroll
    for (int r = 0; r < 4; ++r) {
        int grow = row0 + wave * 16 + q * 4 + r;
        float v[8];
#pragma unroll
        for (int nt = 0; nt < 8; ++nt) v[nt] = acc[nt][r] + bcol[nt];
        if constexpr (EPI == 3) {
            float s = 0.f, ss = 0.f;
#pragma unroll
            for (int nt = 0; nt < 8; ++nt) { s += v[nt]; ss += v[nt] * v[nt]; }
#pragma unroll
            for (int m = 8; m >= 1; m >>= 1) {
                s += __shfl_xor(s, m, 64);
                ss += __shfl_xor(ss, m, 64);
            }
            float mu = s * (1.f / 128.f);
            float var = ss * (1.f / 128.f) - mu * mu;
            float rs = rsqrtf(var + 1e-5f);
#pragma unroll
            for (int nt = 0; nt < 8; ++nt)
                v[nt] = fmaxf((v[nt] - mu) * rs * gcol[nt] + becol[nt], 0.f);
        }
        if (g.aMode > 0) {
            float pa[8];
#pragma unroll
            for (int i = 0; i < 8; ++i) pa[i] = 0.f;
#pragma unroll
            for (int nt = 0; nt < 8; ++nt) {
                int col = nt * 16 + c;
                float2 w0 = *(const float2*)&g.wav0[col * 2];
                pa[0] += v[nt] * w0.x; pa[1] += v[nt] * w0.y;
                if (g.aMode > 1) {
                    float2 w1 = *(const float2*)&g.wav1[col * 2];
                    pa[2] += v[nt] * w1.x; pa[3] += v[nt] * w1.y;
                }
                if (g.aMode > 2) {
                    float2 w2 = *(const float2*)&g.wav2[col * 2];
                    float2 w3 = *(const float2*)&g.wav3[col * 2];
                    pa[4] += v[nt] * w2.x; pa[5] += v[nt] * w2.y;
                    pa[6] += v[nt] * w3.x; pa[7] += v[nt] * w3.y;
                }
            }
#pragma unroll
            for (int m = 8; m >= 1; m >>= 1) {
                pa[0] += __shfl_xor(pa[0], m, 64); pa[1] += __shfl_xor(pa[1], m, 64);
                pa[2] += __shfl_xor(pa[2], m, 64); pa[3] += __shfl_xor(pa[3], m, 64);
                pa[4] += __shfl_xor(pa[4], m, 64); pa[5] += __shfl_xor(pa[5], m, 64);
                pa[6] += __shfl_xor(pa[6], m, 64); pa[7] += __shfl_xor(pa[7], m, 64);
            }
            if (c == 0 && grow < g.M) {
                float* ao = &g.aOut[(size_t)grow * g.aStride];
                ao[0] = pa[0]; ao[1] = pa[1];
                if (g.aMode > 1) { ao[2] = pa[2]; ao[3] = pa[3]; }
                if (g.aMode > 2) { ao[4] = pa[4]; ao[5] = pa[5]; ao[6] = pa[6]; ao[7] = pa[7]; }
            }
        }
        if (grow < g.M) {
            unsigned short* Y = (unsigned short*)g.Y;
#pragma unroll
            for (int nt = 0; nt < 8; ++nt)
                Y[(size_t)grow * g.ldY + nt * 16 + c] = f2bf(v[nt]);
        }
    }
}

// ---------------------------------------------------------------------------
// D2a: tiny bucket scan (1 block) — between prep(hist) and the merged dispatch
// ---------------------------------------------------------------------------
__global__ __launch_bounds__(256) void k_scan(
    const int* __restrict__ bcnt, int* __restrict__ bukoff, int* __restrict__ bukcur) {
    __shared__ int sd[256];
    int t = threadIdx.x;
    int i0 = t * 4;
    int v0 = (i0 < NBUK) ? bcnt[i0] : 0;
    int v1 = (i0 + 1 < NBUK) ? bcnt[i0 + 1] : 0;
    int v2 = (i0 + 2 < NBUK) ? bcnt[i0 + 2] : 0;
    int v3 = (i0 + 3 < NBUK) ? bcnt[i0 + 3] : 0;
    int csum = v0 + v1 + v2 + v3;
    sd[t] = csum;
    __syncthreads();
    for (int off = 1; off < 256; off <<= 1) {
        int tmp = (t >= off) ? sd[t - off] : 0;
        __syncthreads();
        sd[t] += tmp;
        __syncthreads();
    }
    int excl = sd[t] - csum;
    int p0 = excl, p1 = excl + v0, p2 = excl + v0 + v1, p3 = excl + v0 + v1 + v2;
    if (i0 < NBUK) { bukoff[i0] = p0; bukcur[i0] = p0; }
    if (i0 + 1 < NBUK) { bukoff[i0 + 1] = p1; bukcur[i0 + 1] = p1; }
    if (i0 + 2 < NBUK) { bukoff[i0 + 2] = p2; bukcur[i0 + 2] = p2; }
    if (i0 + 3 < NBUK) { bukoff[i0 + 3] = p3; bukcur[i0 + 3] = p3; }
    if (t == 0) bukoff[NBUK] = ETOT;
}

// ---------------------------------------------------------------------------
// D2b: lin0 GEMM (async-staged) blocks + scatter blocks merged in one grid.
// ---------------------------------------------------------------------------
__global__ __launch_bounds__(256) void k_lin0_scat(
    GPair P, int gemmBlocks,
    const int* __restrict__ js_src, const int* __restrict__ js_dst,
    const int* __restrict__ sj_src, const int* __restrict__ sj_dst,
    const int* __restrict__ ss_src, const int* __restrict__ ss_dst,
    int* __restrict__ bukcur, uint2* __restrict__ pairs) {
    if (blockIdx.x < (unsigned)gemmBlocks) {
        mgemm_body<3>(P, blockIdx.x);
        return;
    }
    __shared__ int lh[NBUK];
    __shared__ int lbase[NBUK];
    int t = threadIdx.x;
    int sb = blockIdx.x - gemmBlocks;
    const int CH = (ETOT + SCAT_NB - 1) / SCAT_NB;
    const int beg = sb * CH;
    const int endi = (beg + CH < ETOT) ? beg + CH : ETOT;
    if (beg >= ETOT) return;
    for (int i = t; i < NBUK; i += 256) lh[i] = 0;
    __syncthreads();
    for (int e = beg + t; e < endi; e += 256) {
        int src, bin;
        edge_decode(e, js_src, js_dst, sj_src, sj_dst, ss_src, ss_dst, src, bin);
        atomicAdd(&lh[bin >> 6], 1);
    }
    __syncthreads();
    for (int i = t; i < NBUK; i += 256) {
        int v = lh[i];
        lbase[i] = v ? atomicAdd(&bukcur[i], v) : 0;
    }
    __syncthreads();
    for (int i = t; i < NBUK; i += 256) lh[i] = 0;
    __syncthreads();
    for (int e = beg + t; e < endi; e += 256) {
        int src, bin;
        edge_decode(e, js_src, js_dst, sj_src, sj_dst, ss_src, ss_dst, src, bin);
        int bu = bin >> 6;
        int pos = lbase[bu] + atomicAdd(&lh[bu], 1);
        pairs[pos] = make_uint2((unsigned)src, (unsigned)bin);
    }
}

// ---------------------------------------------------------------------------
// D4: finalize — one block per bucket, dense contiguous esrc writes
// ---------------------------------------------------------------------------
__global__ __launch_bounds__(256) void k_finalize(
    const uint2* __restrict__ pairs, const int* __restrict__ bukoff,
    int* __restrict__ offs, int* __restrict__ esrc) {
    int b = blockIdx.x, t = threadIdx.x;
    int base = bukoff[b], endi = bukoff[b + 1];
    __shared__ int cnt[64], excl[64], curs[64];
    if (t < 64) cnt[t] = 0;
    __syncthreads();
    for (int i = base + t; i < endi; i += 256)
        atomicAdd(&cnt[pairs[i].y & 63], 1);
    __syncthreads();
    if (t < 64) {
        int v = cnt[t];
        int inc = v;
#pragma unroll
        for (int off = 1; off < 64; off <<= 1) {
            int tmp = __shfl_up(inc, off, 64);
            if (t >= off) inc += tmp;
        }
        excl[t] = inc - v;
        curs[t] = inc - v;
    }
    __syncthreads();
    for (int i = base + t; i < endi; i += 256) {
        uint2 p = pairs[i];
        int lb = p.y & 63;
        int pos = atomicAdd(&curs[lb], 1);
        esrc[base + pos] = (int)p.x;
    }
    if (t < 64) {
        int bin = b * 64 + t;
        if (bin < NBINS) offs[bin] = base + excl[t];
    }
    if (b == 0 && t == 0) offs[NBINS] = ETOT;
}

// ---------------------------------------------------------------------------
// Gather v5: deferred projection. Aggregates 128-dim SOURCE features.
// Quarter-wave (16 lanes) per edge, lane = 8 cols (uint4), both heads from one
// row read. Reduce via shfl_xor {16,32}.
// ---------------------------------------------------------------------------
__device__ inline void fm8(float p0, float p1, uint4 u, float a0[8], float a1[8]) {
    float x0 = __uint_as_float(u.x << 16);
    float x1 = __uint_as_float(u.x & 0xffff0000u);
    float x2 = __uint_as_float(u.y << 16);
    float x3 = __uint_as_float(u.y & 0xffff0000u);
    float x4 = __uint_as_float(u.z << 16);
    float x5 = __uint_as_float(u.z & 0xffff0000u);
    float x6 = __uint_as_float(u.w << 16);
    float x7 = __uint_as_float(u.w & 0xffff0000u);
    a0[0] += p0 * x0; a0[1] += p0 * x1; a0[2] += p0 * x2; a0[3] += p0 * x3;
    a0[4] += p0 * x4; a0[5] += p0 * x5; a0[6] += p0 * x6; a0[7] += p0 * x7;
    a1[0] += p1 * x0; a1[1] += p1 * x1; a1[2] += p1 * x2; a1[3] += p1 * x3;
    a1[4] += p1 * x4; a1[5] += p1 * x5; a1[6] += p1 * x6; a1[7] += p1 * x7;
}

__device__ inline void rel_run(
    const int* __restrict__ esrc, int beg, int end,
    const float* __restrict__ aSrc, int aShift, int aOff, float adx, float ady,
    const unsigned short* __restrict__ rows, int colOff, int g,
    float a0[8], float a1[8], float& den0, float& den1) {
    int j = beg;
    for (; j + 8 <= end; j += 8) {
        int s0 = esrc[j + g];
        int s1 = esrc[j + 4 + g];
        uint4 u0 = *(const uint4*)&rows[(unsigned)s0 * 128 + colOff];
        uint4 u1 = *(const uint4*)&rows[(unsigned)s1 * 128 + colOff];
        float2 f0 = *(const float2*)&aSrc[((unsigned)s0 << aShift) + aOff];
        float2 f1 = *(const float2*)&aSrc[((unsigned)s1 << aShift) + aOff];
        float e00 = f0.x + adx; e00 = e00 > 0.f ? e00 : 0.2f * e00;
        float e01 = f0.y + ady; e01 = e01 > 0.f ? e01 : 0.2f * e01;
        float e10 = f1.x + adx; e10 = e10 > 0.f ? e10 : 0.2f * e10;
        float e11 = f1.y + ady; e11 = e11 > 0.f ? e11 : 0.2f * e11;
        float p00 = __expf(e00), p01 = __expf(e01);
        float p10 = __expf(e10), p11 = __expf(e11);
        fm8(p00, p01, u0, a0, a1);
        fm8(p10, p11, u1, a0, a1);
        den0 += p00 + p10; den1 += p01 + p11;
    }
    for (; j < end; j += 4) {
        int e = j + g;
        bool ok = e < end;
        int s = esrc[ok ? e : j];
        uint4 u = *(const uint4*)&rows[(unsigned)s * 128 + colOff];
        float2 f = *(const float2*)&aSrc[((unsigned)s << aShift) + aOff];
        float e0 = f.x + adx; e0 = e0 > 0.f ? e0 : 0.2f * e0;
        float e1 = f.y + ady; e1 = e1 > 0.f ? e1 : 0.2f * e1;
        float p0 = ok ? __expf(e0) : 0.f;
        float p1 = ok ? __expf(e1) : 0.f;
        fm8(p0, p1, u, a0, a1);
        den0 += p0; den1 += p1;
    }
}

__device__ inline void store8(unsigned short* dst, const float v[8]) {
    uint4 o;
    o.x = (unsigned)f2bf(v[0]) | ((unsigned)f2bf(v[1]) << 16);
    o.y = (unsigned)f2bf(v[2]) | ((unsigned)f2bf(v[3]) << 16);
    o.z = (unsigned)f2bf(v[4]) | ((unsigned)f2bf(v[5]) << 16);
    o.w = (unsigned)f2bf(v[6]) | ((unsigned)f2bf(v[7]) << 16);
    *(uint4*)dst = o;
}

__device__ inline void finish_store(float a0[8], float a1[8], float den0, float den1,
                                    int lane, unsigned short* base) {
    float d0 = den0; d0 += __shfl_xor(d0, 16, 64); d0 += __shfl_xor(d0, 32, 64);
    float d1 = den1; d1 += __shfl_xor(d1, 16, 64); d1 += __shfl_xor(d1, 32, 64);
    float s0 = 1.f / (d0 + 1e-16f), s1 = 1.f / (d1 + 1e-16f);
    float o0[8], o1[8];
#pragma unroll
    for (int i = 0; i < 8; ++i) {
        float t0 = a0[i]; t0 += __shfl_xor(t0, 16, 64); t0 += __shfl_xor(t0, 32, 64);
        float t1 = a1[i]; t1 += __shfl_xor(t1, 16, 64); t1 += __shfl_xor(t1, 32, 64);
        o0[i] = t0 * s0; o1[i] = t1 * s1;
    }
    if ((lane >> 4) == 0) {
        store8(base, o0);
        store8(base + 128, o1);
    }
}

__global__ __launch_bounds__(256) void k_gather_all(
    const int* __restrict__ offs, const int* __restrict__ esrc,
    const float* __restrict__ aJ, const float* __restrict__ aS,
    const unsigned short* __restrict__ rowsJ,   // job src rows (ld 128)
    const unsigned short* __restrict__ rowsS,   // skill src rows (ld 128)
    unsigned short* __restrict__ aggS,          // [NS][512]: jsH0|jsH1|ssH0|ssH1
    unsigned short* __restrict__ aggJ,          // [NJ][256]: sjH0|sjH1
    int jobOnly) {
    int wave = threadIdx.x >> 6, lane = threadIdx.x & 63;
    int idx = blockIdx.x * 4 + wave;
    int g = lane >> 4, cl = lane & 15;
    int colOff = cl * 8;

    float a0[8], a1[8], den0, den1;

    if (jobOnly) {
        if (idx >= NJ) return;
        int d = idx;
#pragma unroll
        for (int i = 0; i < 8; ++i) { a0[i] = 0.f; a1[i] = 0.f; }
        den0 = den1 = 0.f;
        int bb = NS + d;
        float2 ad = *(const float2*)&aJ[(unsigned)d * 4 + 2];
        rel_run(esrc, offs[bb], offs[bb + 1], aS, 3, 4, ad.x, ad.y, rowsS, colOff, g, a0, a1, den0, den1);
        finish_store(a0, a1, den0, den1, lane, &aggJ[(size_t)d * 256 + colOff]);
        return;
    }
    if (idx < NS) {
        int d = idx;
#pragma unroll
        for (int i = 0; i < 8; ++i) { a0[i] = 0.f; a1[i] = 0.f; }
        den0 = den1 = 0.f;
        float2 adA = *(const float2*)&aS[(unsigned)d * 8 + 2];
        rel_run(esrc, offs[d], offs[d + 1], aJ, 2, 0, adA.x, adA.y, rowsJ, colOff, g, a0, a1, den0, den1);
        finish_store(a0, a1, den0, den1, lane, &aggS[(size_t)d * 512 + colOff]);
#pragma unroll
        for (int i = 0; i < 8; ++i) { a0[i] = 0.f; a1[i] = 0.f; }
        den0 = den1 = 0.f;
        int bb = NS + NJ + d;
        float2 adB = *(const float2*)&aS[(unsigned)d * 8 + 6];
        rel_run(esrc, offs[bb], offs[bb + 1], aS, 3, 0, adB.x, adB.y, rowsS, colOff, g, a0, a1, den0, den1);
        finish_store(a0, a1, den0, den1, lane, &aggS[(size_t)d * 512 + 256 + colOff]);
    } else if (idx < NS + NJ) {
        int d = idx - NS;
#pragma unroll
        for (int i = 0; i < 8; ++i) { a0[i] = 0.f; a1[i] = 0.f; }
        den0 = den1 = 0.f;
        int bb = NS + d;
        float2 ad = *(const float2*)&aJ[(unsigned)d * 4 + 2];
        rel_run(esrc, offs[bb], offs[bb + 1], aS, 3, 4, ad.x, ad.y, rowsS, colOff, g, a0, a1, den0, den1);
        finish_store(a0, a1, den0, den1, lane, &aggJ[(size_t)d * 256 + colOff]);
    }
}

// ---------------------------------------------------------------------------
// D6: two-stage fused GEMM, LDS-lean. Per np half (128 cols of stage1 out):
// stage1 K-loop -> Y1l[4] (half), then stage2 K-slice accumulates into acc2
// registers. LDS = Al(5K)+Bl(10K)+Y1l(20.5K) = 35.8KB -> 4 blocks/CU.
// ---------------------------------------------------------------------------
struct FJob {
    const unsigned short* X; int K1; int M;
    const unsigned short* Wt1; const float* bias1;
    const unsigned short* Wt2; const float* bias2;
    const float* wa; float* aOut; int aStride;
    unsigned short* Y2;                          // nullable; ld 128
};
struct FPair { FJob a; FJob b; int blocksA; };

__global__ __launch_bounds__(256) void k_fused2(FPair P) {
    int mb = blockIdx.x;
    FJob g = (mb < P.blocksA) ? P.a : P.b;
    if (mb >= P.blocksA) mb -= P.blocksA;
    const int row0 = mb * 64;
    const int K1 = g.K1;

    __shared__ __align__(16) unsigned short Al[64][40];
    __shared__ __align__(16) unsigned short Bl[128][40];
    __shared__ __align__(16) unsigned short Y1l[4][64][40];
    const int t = threadIdx.x;
    const int wave = t >> 6, lane = t & 63;
    const int q = lane >> 4, c = lane & 15;

    f4_t acc2[8];
#pragma unroll
    for (int nt = 0; nt < 8; ++nt) acc2[nt] = (f4_t){0.f, 0.f, 0.f, 0.f};

    for (int np = 0; np < 2; ++np) {
        f4_t acc[8];
#pragma unroll
        for (int nt = 0; nt < 8; ++nt) acc[nt] = (f4_t){0.f, 0.f, 0.f, 0.f};
        for (int k0 = 0; k0 < K1; k0 += 32) {
#pragma unroll
            for (int it = 0; it < 3; ++it) {
                int idx = t + it * 256;
                int r = idx >> 2, cc = (idx & 3) * 8;
                if (r < 64) {
                    int gr = row0 + r;
                    uint4 va = (gr < g.M) ? *(const uint4*)&g.X[(size_t)gr * K1 + k0 + cc]
                                          : make_uint4(0u, 0u, 0u, 0u);
                    *(uint4*)&Al[r][cc] = va;
                } else {
                    int br = r - 64;
                    *(uint4*)&Bl[br][cc] = *(const uint4*)&g.Wt1[(size_t)(np * 128 + br) * K1 + k0 + cc];
                }
            }
            __syncthreads();
            bf8_t af = *(const bf8_t*)&Al[wave * 16 + c][q * 8];
#pragma unroll
            for (int nt = 0; nt < 8; ++nt) {
                bf8_t bfr = *(const bf8_t*)&Bl[nt * 16 + c][q * 8];
                acc[nt] = __builtin_amdgcn_mfma_f32_16x16x32_bf16(af, bfr, acc[nt], 0, 0, 0);
            }
            __syncthreads();
        }
        float bcol[8];
#pragma unroll
        for (int nt = 0; nt < 8; ++nt) bcol[nt] = g.bias1[np * 128 + nt * 16 + c];
#pragma unroll
        for (int r = 0; r < 4; ++r) {
            int row = wave * 16 + q * 4 + r;
#pragma unroll
            for (int nt = 0; nt < 8; ++nt)
                Y1l[nt >> 1][row][(nt & 1) * 16 + c] = f2bf(acc[nt][r] + bcol[nt]);
        }
        __syncthreads();
        // stage2 partial: K-slice np*128 .. np*128+127
        for (int k0 = 0; k0 < 128; k0 += 32) {
#pragma unroll
            for (int it = 0; it < 2; ++it) {
                int idx = t + it * 256;
                int br = idx >> 2, cc = (idx & 3) * 8;
                *(uint4*)&Bl[br][cc] = *(const uint4*)&g.Wt2[(size_t)br * 256 + np * 128 + k0 + cc];
            }
            __syncthreads();
            bf8_t af = *(const bf8_t*)&Y1l[k0 >> 5][wave * 16 + c][q * 8];
#pragma unroll
            for (int nt = 0; nt < 8; ++nt) {
                bf8_t bfr = *(const bf8_t*)&Bl[nt * 16 + c][q * 8];
                acc2[nt] = __builtin_amdgcn_mfma_f32_16x16x32_bf16(af, bfr, acc2[nt], 0, 0, 0);
            }
            __syncthreads();
        }
    }

    float b2[8];
#pragma unroll
    for (int nt = 0; nt < 8; ++nt) b2[nt] = g.bias2[nt * 16 + c];
#pragma unroll
    for (int r = 0; r < 4; ++r) {
        int grow = row0 + wave * 16 + q * 4 + r;
        float v[8];
#pragma unroll
        for (int nt = 0; nt < 8; ++nt) v[nt] = fmaxf(acc2[nt][r] + b2[nt], 0.f);
        if (g.wa) {
            float pa0 = 0.f, pa1 = 0.f;
#pragma unroll
            for (int nt = 0; nt < 8; ++nt) {
                float2 w0 = *(const float2*)&g.wa[(nt * 16 + c) * 2];
                pa0 += v[nt] * w0.x; pa1 += v[nt] * w0.y;
            }
#pragma unroll
            for (int m = 8; m >= 1; m >>= 1) {
                pa0 += __shfl_xor(pa0, m, 64);
                pa1 += __shfl_xor(pa1, m, 64);
            }
            if (c == 0 && grow < g.M) {
                g.aOut[(size_t)grow * g.aStride + 0] = pa0;
                g.aOut[(size_t)grow * g.aStride + 1] = pa1;
            }
        }
        if (g.Y2 && grow < g.M) {
#pragma unroll
            for (int nt = 0; nt < 8; ++nt)
                g.Y2[(size_t)grow * 128 + nt * 16 + c] = f2bf(v[nt]);
        }
    }
}

// ---------------------------------------------------------------------------
// D8: three-stage fused GEMM, LDS-lean. Same np-interleave as k_fused2; the
// Yl buffer is reused for stage2's output (stage3 input). 35.8KB LDS.
// ---------------------------------------------------------------------------
struct F3 {
    const unsigned short* X; int M;
    const unsigned short* Wt1; const float* bias1;
    const unsigned short* Wt2; const float* bias2;
    const unsigned short* Wt3; const float* bias3;
    const float* qv; float* sc; float* Y;
};

__global__ __launch_bounds__(256) void k_fused3(F3 g) {
    int mb = blockIdx.x;
    const int row0 = mb * 64;
    __shared__ __align__(16) unsigned short Al[64][40];
    __shared__ __align__(16) unsigned short Bl[128][40];
    __shared__ __align__(16) unsigned short Yl[4][64][40];
    const int t = threadIdx.x;
    const int wave = t >> 6, lane = t & 63;
    const int q = lane >> 4, c = lane & 15;

    f4_t acc2[8];
#pragma unroll
    for (int nt = 0; nt < 8; ++nt) acc2[nt] = (f4_t){0.f, 0.f, 0.f, 0.f};

    for (int np = 0; np < 2; ++np) {
        f4_t acc[8];
#pragma unroll
        for (int nt = 0; nt < 8; ++nt) acc[nt] = (f4_t){0.f, 0.f, 0.f, 0.f};
        for (int k0 = 0; k0 < 256; k0 += 32) {
#pragma unroll
            for (int it = 0; it < 3; ++it) {
                int idx = t + it * 256;
                int r = idx >> 2, cc = (idx & 3) * 8;
                if (r < 64) {
                    int gr = row0 + r;
                    uint4 va = (gr < g.M) ? *(const uint4*)&g.X[(size_t)gr * 256 + k0 + cc]
                                          : make_uint4(0u, 0u, 0u, 0u);
                    *(uint4*)&Al[r][cc] = va;
                } else {
                    int br = r - 64;
                    *(uint4*)&Bl[br][cc] = *(const uint4*)&g.Wt1[(size_t)(np * 128 + br) * 256 + k0 + cc];
                }
            }
            __syncthreads();
            bf8_t af = *(const bf8_t*)&Al[wave * 16 + c][q * 8];
#pragma unroll
            for (int nt = 0; nt < 8; ++nt) {
                bf8_t bfr = *(const bf8_t*)&Bl[nt * 16 + c][q * 8];
                acc[nt] = __builtin_amdgcn_mfma_f32_16x16x32_bf16(af, bfr, acc[nt], 0, 0, 0);
            }
            __syncthreads();
        }
        float bcol[8];
#pragma unroll
        for (int nt = 0; nt < 8; ++nt) bcol[nt] = g.bias1[np * 128 + nt * 16 + c];
#pragma unroll
        for (int r = 0; r < 4; ++r) {
            int row = wave * 16 + q * 4 + r;
#pragma unroll
            for (int nt = 0; nt < 8; ++nt)
                Yl[nt >> 1][row][(nt & 1) * 16 + c] = f2bf(acc[nt][r] + bcol[nt]);
        }
        __syncthreads();
        for (int k0 = 0; k0 < 128; k0 += 32) {
#pragma unroll
            for (int it = 0; it < 2; ++it) {
                int idx = t + it * 256;
                int br = idx >> 2, cc = (idx & 3) * 8;
                *(uint4*)&Bl[br][cc] = *(const uint4*)&g.Wt2[(size_t)br * 256 + np * 128 + k0 + cc];
            }
            __syncthreads();
            bf8_t af = *(const bf8_t*)&Yl[k0 >> 5][wave * 16 + c][q * 8];
#pragma unroll
            for (int nt = 0; nt < 8; ++nt) {
                bf8_t bfr = *(const bf8_t*)&Bl[nt * 16 + c][q * 8];
                acc2[nt] = __builtin_amdgcn_mfma_f32_16x16x32_bf16(af, bfr, acc2[nt], 0, 0, 0);
            }
            __syncthreads();
        }
    }

    // stage2 epilogue: bias + relu -> Yl (reused; prior contents fully consumed)
    {
        float b2[8];
#pragma unroll
        for (int nt = 0; nt < 8; ++nt) b2[nt] = g.bias2[nt * 16 + c];
#pragma unroll
        for (int r = 0; r < 4; ++r) {
            int row = wave * 16 + q * 4 + r;
#pragma unroll
            for (int nt = 0; nt < 8; ++nt)
                Yl[nt >> 1][row][(nt & 1) * 16 + c] = f2bf(fmaxf(acc2[nt][r] + b2[nt], 0.f));
        }
        __syncthreads();
    }

    // stage3: 128 -> 128, f32 out + scores
    f4_t acc3[8];
#pragma unroll
    for (int nt = 0; nt < 8; ++nt) acc3[nt] = (f4_t){0.f, 0.f, 0.f, 0.f};
    for (int k0 = 0; k0 < 128; k0 += 32) {
#pragma unroll
        for (int it = 0; it < 2; ++it) {
            int idx = t + it * 256;
            int br = idx >> 2, cc = (idx & 3) * 8;
            *(uint4*)&Bl[br][cc] = *(const uint4*)&g.Wt3[(size_t)br * 128 + k0 + cc];
        }
        __syncthreads();
        bf8_t af = *(const bf8_t*)&Yl[k0 >> 5][wave * 16 + c][q * 8];
#pragma unroll
        for (int nt = 0; nt < 8; ++nt) {
            bf8_t bfr = *(const bf8_t*)&Bl[nt * 16 + c][q * 8];
            acc3[nt] = __builtin_amdgcn_mfma_f32_16x16x32_bf16(af, bfr, acc3[nt], 0, 0, 0);
        }
        __syncthreads();
    }
    float b3[8], qcol[8];
#pragma unroll
    for (int nt = 0; nt < 8; ++nt) {
        b3[nt] = g.bias3[nt * 16 + c];
        qcol[nt] = g.qv[nt * 16 + c];
    }
#pragma unroll
    for (int r = 0; r < 4; ++r) {
        int grow = row0 + wave * 16 + q * 4 + r;
        float v[8];
#pragma unroll
        for (int nt = 0; nt < 8; ++nt) v[nt] = acc3[nt][r] + b3[nt];
        float part = 0.f;
#pragma unroll
        for (int nt = 0; nt < 8; ++nt) part += v[nt] * qcol[nt];
#pragma unroll
        for (int m = 8; m >= 1; m >>= 1) part += __shfl_xor(part, m, 64);
        if (grow < g.M) {
            if (c == 0) g.sc[grow] = part;
#pragma unroll
            for (int nt = 0; nt < 8; ++nt)
                g.Y[(size_t)grow * 128 + nt * 16 + c] = v[nt];
        }
    }
}

// ---------------------------------------------------------------------------
extern "C" void kernel_launch(void* const* d_in, const int* in_sizes, int n_in,
                              void* d_out, int out_size, void* d_ws, size_t ws_size,
                              hipStream_t stream) {
    const float* x_job   = (const float*)d_in[0];
    const float* x_skill = (const float*)d_in[1];
    const int* js_src = (const int*)d_in[2];
    const int* js_dst = (const int*)d_in[3];
    const int* sj_src = (const int*)d_in[4];
    const int* sj_dst = (const int*)d_in[5];
    const int* ss_src = (const int*)d_in[6];
    const int* ss_dst = (const int*)d_in[7];
    const float* query    = (const float*)d_in[8];
    const float* W0_job   = (const float*)d_in[9];
    const float* b0_job   = (const float*)d_in[10];
    const float* g0_job   = (const float*)d_in[11];
    const float* be0_job  = (const float*)d_in[12];
    const float* W0_skill = (const float*)d_in[13];
    const float* b0_skill = (const float*)d_in[14];
    const float* g0_skill = (const float*)d_in[15];
    const float* be0_skill= (const float*)d_in[16];
    const float* gat_Ws = (const float*)d_in[17];
    const float* gat_Wd = (const float*)d_in[18];
    const float* gat_as = (const float*)d_in[19];
    const float* gat_ad = (const float*)d_in[20];
    const float* gat_b  = (const float*)d_in[21];
    const float* inter_W = (const float*)d_in[22];
    const float* inter_b = (const float*)d_in[23];
    const float* Wjf = (const float*)d_in[24];
    const float* bjf = (const float*)d_in[25];
    const float* Wq  = (const float*)d_in[26];
    const float* bq  = (const float*)d_in[27];

    char* w = (char*)d_ws;
    auto alloc = [&](size_t bytes) -> void* {
        void* p = (void*)w;
        w += (bytes + 255) & ~(size_t)255;
        return p;
    };
    u16* xj   = (u16*)alloc((size_t)NJ * 128 * 2);
    u16* xs   = (u16*)alloc((size_t)NS * 128 * 2);
    u16* xs1  = (u16*)alloc((size_t)NS * 128 * 2);
    u16* aggJ  = (u16*)alloc((size_t)NJ * 256 * 2);
    u16* aggJ1 = (u16*)alloc((size_t)NJ * 256 * 2);
    u16* aggS  = (u16*)alloc((size_t)NS * 512 * 2);
    u16* WtW0j = (u16*)alloc((size_t)SBERT * 128 * 2);
    u16* WtW0s = (u16*)alloc((size_t)SBERT * 128 * 2);
    u16* WsS1  = (u16*)alloc((size_t)256 * 512 * 2);
    u16* WsJ0  = (u16*)alloc((size_t)256 * 256 * 2);
    u16* WsJ1  = (u16*)alloc((size_t)256 * 256 * 2);
    u16* WtI00 = (u16*)alloc((size_t)128 * 256 * 2);
    u16* WtI01 = (u16*)alloc((size_t)128 * 256 * 2);
    u16* WtI10 = (u16*)alloc((size_t)128 * 256 * 2);
    u16* WtJf  = (u16*)alloc((size_t)128 * 128 * 2);
    float* gbS = (float*)alloc(256 * 4);
    float* aJ = (float*)alloc((size_t)NJ * 4 * 4);
    float* aS = (float*)alloc((size_t)NS * 8 * 4);
    float* wsa = (float*)alloc(6 * 256 * 4);
    float* wda = (float*)alloc(6 * 256 * 4);
    int* bcnt   = (int*)alloc((size_t)NBUK * 4);
    int* bukoff = (int*)alloc((size_t)(NBUK + 1) * 4);
    int* bukcur = (int*)alloc((size_t)NBUK * 4);
    uint2* pairs = (uint2*)alloc((size_t)ETOT * 8);
    int* offs = (int*)alloc((size_t)(NBINS + 1) * 4);
    int* esrc = (int*)alloc((size_t)ETOT * 4);

    float* out = (float*)d_out;
    float* scores  = out;
    float* job_emb = out + NJ;
    float* qv      = out + NJ + (size_t)NJ * 128;

    const int mbJ = cdiv(NJ, 64);   // 469
    const int mbS = cdiv(NS, 64);   // 188
    const int gemmB = mbJ + mbS;    // 657

    // M0: zero bucket counters + structured weight buffers (block layouts)
    hipMemsetAsync(bcnt, 0, (size_t)NBUK * 4, stream);
    hipMemsetAsync(WsS1, 0, (size_t)256 * 512 * 2, stream);
    hipMemsetAsync(WsJ0, 0, (size_t)256 * 256 * 2, stream);
    hipMemsetAsync(WsJ1, 0, (size_t)256 * 256 * 2, stream);

    // D1: prep (weight casts/structured layouts + wa + qvec + gbS + hist)
    {
        const size_t WS = (size_t)128 * 256;
        const size_t IW = (size_t)256 * 128;
        PrepArgs A;
        A.m[0]  = {W0_job,   WtW0j, SBERT, 128, 128, SBERT};
        A.m[1]  = {W0_skill, WtW0s, SBERT, 128, 128, SBERT};
        // WsS1 (256x512): [n<128,k<128]=Ws00[:,:128]; [n>=128,k 128..256)=Ws00[:,128:]
        //                 [n<128,k 256..384)=Ws02[:,:128]; [n>=128,k 384..512)=Ws02[:,128:]
        A.m[2]  = {gat_Ws + 0 * WS,       WsS1,                       128, 128, 256, 512};
        A.m[3]  = {gat_Ws + 0 * WS + 128, WsS1 + 128 * 512 + 128,     128, 128, 256, 512};
        A.m[4]  = {gat_Ws + 2 * WS,       WsS1 + 256,                 128, 128, 256, 512};
        A.m[5]  = {gat_Ws + 2 * WS + 128, WsS1 + 128 * 512 + 384,     128, 128, 256, 512};
        // WsJ0 (256x256): block-diag from Ws01
        A.m[6]  = {gat_Ws + 1 * WS,       WsJ0,                       128, 128, 256, 256};
        A.m[7]  = {gat_Ws + 1 * WS + 128, WsJ0 + 128 * 256 + 128,     128, 128, 256, 256};
        // WsJ1 (256x256): block-diag from Ws11
        A.m[8]  = {gat_Ws + 4 * WS,       WsJ1,                       128, 128, 256, 256};
        A.m[9]  = {gat_Ws + 4 * WS + 128, WsJ1 + 128 * 256 + 128,     128, 128, 256, 256};
        A.m[10] = {inter_W + 0 * IW, WtI00, 256, 128, 128, 256};
        A.m[11] = {inter_W + 1 * IW, WtI01, 256, 128, 128, 256};
        A.m[12] = {inter_W + 2 * IW, WtI10, 256, 128, 128, 256};
        A.m[13] = {Wjf, WtJf, 128, 128, 128, 128};
        A.Ws = gat_Ws; A.as_ = gat_as; A.Wd = gat_Wd; A.ad_ = gat_ad;
        A.wsa = wsa; A.wda = wda; A.bcnt = bcnt;
        A.query = query; A.Wq = Wq; A.bq = bq; A.qv = qv;
        A.gat_b = gat_b; A.gbS = gbS;
        A.js_src = js_src; A.js_dst = js_dst;
        A.sj_src = sj_src; A.sj_dst = sj_dst;
        A.ss_src = ss_src; A.ss_dst = ss_dst;
        k_prep<<<PREP_HIST + HIST_NB, 256, 0, stream>>>(A);
    }

    // D2a: bucket scan (1 block)
    k_scan<<<1, 256, 0, stream>>>(bcnt, bukoff, bukcur);

    // D2b: lin0 GEMM (async gload_lds staging) + scatter blocks merged
    {
        GPair P;
        P.a = {x_job, WtW0j, b0_job, g0_job, be0_job, xj, NJ, SBERT, 128, 128, 1,
               nullptr, nullptr, 2, wsa + 0, wda + 256, nullptr, nullptr, aJ, 4};
        P.b = {x_skill, WtW0s, b0_skill, g0_skill, be0_skill, xs, NS, SBERT, 128, 128, 1,
               nullptr, nullptr, 4, wsa + 2 * 256, wda + 0, wsa + 1 * 256, wda + 2 * 256, aS, 8};
        P.blocksA = mbJ;
        k_lin0_scat<<<gemmB + SCAT_NB, 256, 0, stream>>>(
            P, gemmB, js_src, js_dst, sj_src, sj_dst, ss_src, ss_dst, bukcur, pairs);
    }

    // D4: finalize CSR
    k_finalize<<<NBUK, 256, 0, stream>>>(pairs, bukoff, offs, esrc);

    // D5: gather l0 — aggregate 128-dim source features (both heads)
    k_gather_all<<<cdiv(NS + NJ, 4), 256, 0, stream>>>(
        offs, esrc, aJ, aS, xj, xs, aggS, aggJ, 0);

    // D6: fused Ws-proj + inter (relu) + alpha-l1. Job: no Y2 store needed.
    {
        FPair P;
        P.a = {aggJ, 256, NJ, WsJ0, gat_b + 256, WtI00, inter_b + 0,
               wda + 4 * 256, aJ + 2, 4, nullptr};
        P.b = {aggS, 512, NS, WsS1, gbS, WtI01, inter_b + 128,
               wsa + 4 * 256, aS + 4, 8, xs1};
        P.blocksA = mbJ;
        k_fused2<<<gemmB, 256, 0, stream>>>(P);
    }

    // D7: gather l1 (job dsts only; srcs are xs1, 3MB working set)
    k_gather_all<<<cdiv(NJ, 4), 256, 0, stream>>>(
        offs, esrc, aJ, aS, nullptr, xs1, nullptr, aggJ1, 1);

    // D8: fused Ws-proj + inter(relu) + final projection + scores (mbJ blocks!)
    {
        F3 g3;
        g3.X = aggJ1; g3.M = NJ;
        g3.Wt1 = WsJ1; g3.bias1 = gat_b + 4 * 256;
        g3.Wt2 = WtI10; g3.bias2 = inter_b + 2 * 128;
        g3.Wt3 = WtJf; g3.bias3 = bjf;
        g3.qv = qv; g3.sc = scores; g3.Y = job_emb;
        k_fused3<<<mbJ, 256, 0, stream>>>(g3);
    }
}